// Round 2
// baseline (954.007 us; speedup 1.0000x reference)
//
#include <hip/hip_runtime.h>
#include <hip/hip_bf16.h>
#include <cstdint>
#include <cstddef>

// Problem dims
#define HD   768
#define ID   3072
#define NB   4
#define SL   2048
#define NL   4
#define ROWS (NB*SL)   // 8192

typedef __attribute__((ext_vector_type(8))) short bf16x8s;
typedef __attribute__((ext_vector_type(4))) float f32x4;

// ---------------------------------------------------------------------------
// LayerNorm body (row of 768, block of 256 threads, 3 elems/thread)
// ---------------------------------------------------------------------------
__device__ __forceinline__ void ln_body(float v[3], int tid,
    const float* __restrict__ scale, const float* __restrict__ bias,
    float* __restrict__ outf, __hip_bfloat16* __restrict__ outb,
    size_t rowoff, bool wb)
{
  __shared__ float red[8];
  float s = v[0] + v[1] + v[2];
#pragma unroll
  for (int off = 32; off; off >>= 1) s += __shfl_down(s, off);
  if ((tid & 63) == 0) red[tid >> 6] = s;
  __syncthreads();
  float mean = (red[0] + red[1] + red[2] + red[3]) * (1.0f / 768.0f);
  float q = 0.f;
#pragma unroll
  for (int i = 0; i < 3; i++) { float d = v[i] - mean; q += d * d; }
#pragma unroll
  for (int off = 32; off; off >>= 1) q += __shfl_down(q, off);
  if ((tid & 63) == 0) red[4 + (tid >> 6)] = q;
  __syncthreads();
  float rstd = rsqrtf((red[4] + red[5] + red[6] + red[7]) * (1.0f / 768.0f) + 1e-5f);
#pragma unroll
  for (int i = 0; i < 3; i++) {
    int j = tid + i * 256;
    float o = (v[i] - mean) * rstd * scale[j] + bias[j];
    outf[rowoff + j] = o;
    if (wb) outb[rowoff + j] = __float2bfloat16(o);
  }
}

// embedding gather + pos add + LN
__global__ __launch_bounds__(256) void embed_ln_kernel(
    const int* __restrict__ ids, const float* __restrict__ wemb,
    const float* __restrict__ pemb,
    const float* __restrict__ scale, const float* __restrict__ bias,
    float* __restrict__ outf, __hip_bfloat16* __restrict__ outb)
{
  int row = blockIdx.x;           // b*SL + t
  int t = row & (SL - 1);
  int id = ids[row];
  int tid = threadIdx.x;
  float v[3];
#pragma unroll
  for (int i = 0; i < 3; i++) {
    int j = tid + i * 256;
    v[i] = wemb[(size_t)id * HD + j] + pemb[(size_t)t * HD + j];
  }
  ln_body(v, tid, scale, bias, outf, outb, (size_t)row * HD, true);
}

// (optional residual add) + LN
template <int ADD, int WB>
__global__ __launch_bounds__(256) void ln_kernel(
    const float* __restrict__ x, const float* __restrict__ y,
    const float* __restrict__ scale, const float* __restrict__ bias,
    float* __restrict__ outf, __hip_bfloat16* __restrict__ outb)
{
  int row = blockIdx.x;
  int tid = threadIdx.x;
  const float* xr = x + (size_t)row * HD;
  const float* yr = y + (size_t)row * HD;
  float v[3];
#pragma unroll
  for (int i = 0; i < 3; i++) {
    int j = tid + i * 256;
    v[i] = xr[j];
    if (ADD) v[i] += yr[j];
  }
  ln_body(v, tid, scale, bias, outf, outb, (size_t)row * HD, WB != 0);
}

// ---------------------------------------------------------------------------
// Weight transpose + f32->bf16: in [K][N] f32 -> out [N][K] bf16, grid.z = layer
// ---------------------------------------------------------------------------
__global__ __launch_bounds__(256) void transpose_bf16_kernel(
    const float* __restrict__ in, __hip_bfloat16* __restrict__ out, int K, int N)
{
  __shared__ float tile[32][33];
  const float* inp = in + (size_t)blockIdx.z * K * N;
  __hip_bfloat16* outp = out + (size_t)blockIdx.z * K * N;
  int n0 = blockIdx.x * 32, k0 = blockIdx.y * 32;
  int tx = threadIdx.x, ty = threadIdx.y;   // (32, 8)
#pragma unroll
  for (int i = 0; i < 4; i++)
    tile[ty + i * 8][tx] = inp[(size_t)(k0 + ty + i * 8) * N + n0 + tx];
  __syncthreads();
#pragma unroll
  for (int i = 0; i < 4; i++)
    outp[(size_t)(n0 + ty + i * 8) * K + k0 + tx] = __float2bfloat16(tile[tx][ty + i * 8]);
}

// ---------------------------------------------------------------------------
// Retention decay scan: r_t = 0.5*s_t + 0.5*r_{t-1}. Chunked (128/chunk) with
// 64-step warm-up (0.5^64 ~ 5e-20 -> exact to fp32).
// ---------------------------------------------------------------------------
__global__ __launch_bounds__(256) void scan_kernel(
    const float* __restrict__ s, float* __restrict__ r)
{
  int bid = blockIdx.x;             // b*48 + chunk*3 + sub
  int sub = bid % 3;
  int chunk = (bid / 3) % 16;
  int b = bid / 48;
  int h = sub * 256 + threadIdx.x;
  int tstart = chunk * 128;
  int t0 = tstart - 64; if (t0 < 0) t0 = 0;
  const float* sp = s + (size_t)b * SL * HD + h;
  float* rp = r + (size_t)b * SL * HD + h;
  float acc = 0.f;
#pragma unroll 8
  for (int t = t0; t < tstart; ++t)
    acc = 0.5f * (sp[(size_t)t * HD] + acc);
#pragma unroll 8
  for (int t = tstart; t < tstart + 128; ++t) {
    acc = 0.5f * (sp[(size_t)t * HD] + acc);
    rp[(size_t)t * HD] = acc;
  }
}

// ---------------------------------------------------------------------------
// GEMM: C[M,N] = act(A[M,K] @ Bt[N,K]^T + bias), A/Bt bf16, acc f32.
// BM=128, BN=64, BK=32; 256 threads = 4 waves stacked in M; 2x4 frags/wave.
// ACT: 0 none, 1 sigmoid, 2 gelu(tanh). WF: write f32 C. WB: write bf16 C.
// ---------------------------------------------------------------------------
template <int ACT, int WF, int WB>
__global__ __launch_bounds__(256) void gemm_bt_kernel(
    const __hip_bfloat16* __restrict__ A,
    const __hip_bfloat16* __restrict__ Bt,
    const float* __restrict__ bias,
    float* __restrict__ Cf, __hip_bfloat16* __restrict__ Cb,
    int M, int N, int K)
{
  const int BK = 32;
  __shared__ __align__(16) __hip_bfloat16 As[128][40];   // padded stride 80B
  __shared__ __align__(16) __hip_bfloat16 Bs[64][40];
  int m0 = blockIdx.x * 128;
  int n0 = blockIdx.y * 64;
  int tid = threadIdx.x;
  int lane = tid & 63;
  int w = tid >> 6;          // wave 0..3 -> rows w*32..w*32+31
  int lr = lane & 15;
  int kg = lane >> 4;        // 0..3

  f32x4 acc[2][4];
#pragma unroll
  for (int i = 0; i < 2; i++)
#pragma unroll
    for (int j = 0; j < 4; j++) acc[i][j] = (f32x4){0.f, 0.f, 0.f, 0.f};

  int sr = tid >> 2;          // 0..63
  int sc = (tid & 3) * 8;     // 0,8,16,24

  for (int k0 = 0; k0 < K; k0 += BK) {
    *reinterpret_cast<uint4*>(&As[sr][sc]) =
        *reinterpret_cast<const uint4*>(&A[(size_t)(m0 + sr) * K + k0 + sc]);
    *reinterpret_cast<uint4*>(&As[sr + 64][sc]) =
        *reinterpret_cast<const uint4*>(&A[(size_t)(m0 + sr + 64) * K + k0 + sc]);
    *reinterpret_cast<uint4*>(&Bs[sr][sc]) =
        *reinterpret_cast<const uint4*>(&Bt[(size_t)(n0 + sr) * K + k0 + sc]);
    __syncthreads();

    bf16x8s a[2], b[4];
#pragma unroll
    for (int i = 0; i < 2; i++)
      a[i] = *reinterpret_cast<const bf16x8s*>(&As[w * 32 + i * 16 + lr][kg * 8]);
#pragma unroll
    for (int j = 0; j < 4; j++)
      b[j] = *reinterpret_cast<const bf16x8s*>(&Bs[j * 16 + lr][kg * 8]);
#pragma unroll
    for (int i = 0; i < 2; i++)
#pragma unroll
      for (int j = 0; j < 4; j++)
        acc[i][j] = __builtin_amdgcn_mfma_f32_16x16x32_bf16(a[i], b[j], acc[i][j], 0, 0, 0);
    __syncthreads();
  }

#pragma unroll
  for (int i = 0; i < 2; i++)
#pragma unroll
    for (int j = 0; j < 4; j++) {
      int col = n0 + j * 16 + lr;
      float bv = bias[col];
#pragma unroll
      for (int r = 0; r < 4; r++) {
        int row = m0 + w * 32 + i * 16 + kg * 4 + r;
        float v = acc[i][j][r] + bv;
        if (ACT == 1) v = 1.f / (1.f + __expf(-v));
        else if (ACT == 2) {
          float x = v;
          v = 0.5f * x * (1.f + tanhf(0.7978845608028654f * (x + 0.044715f * x * x * x)));
        }
        if (WF) Cf[(size_t)row * N + col] = v;
        if (WB) Cb[(size_t)row * N + col] = __float2bfloat16(v);
      }
    }
}

// ---------------------------------------------------------------------------
extern "C" void kernel_launch(void* const* d_in, const int* in_sizes, int n_in,
                              void* d_out, int out_size, void* d_ws, size_t ws_size,
                              hipStream_t stream)
{
  const int*   ids  = (const int*)d_in[0];
  const float* wemb = (const float*)d_in[1];
  const float* pemb = (const float*)d_in[2];
  const float* elns = (const float*)d_in[3];
  const float* elnb = (const float*)d_in[4];
  const float* retW = (const float*)d_in[5];
  const float* retb = (const float*)d_in[6];
  const float* ln1s = (const float*)d_in[7];
  const float* ln1b = (const float*)d_in[8];
  const float* W1   = (const float*)d_in[9];
  const float* b1   = (const float*)d_in[10];
  const float* W2   = (const float*)d_in[11];
  const float* b2   = (const float*)d_in[12];
  const float* ln2s = (const float*)d_in[13];
  const float* ln2b = (const float*)d_in[14];
  const float* fins = (const float*)d_in[15];
  const float* finb = (const float*)d_in[16];
  float* out = (float*)d_out;

  char* ws = (char*)d_ws;
  size_t off = 0;
  __hip_bfloat16* retWt = (__hip_bfloat16*)(ws + off); off += (size_t)NL * HD * HD * 2;
  __hip_bfloat16* W1t   = (__hip_bfloat16*)(ws + off); off += (size_t)NL * HD * ID * 2;
  __hip_bfloat16* W2t   = (__hip_bfloat16*)(ws + off); off += (size_t)NL * ID * HD * 2;
  float*          hf    = (float*)(ws + off);          off += (size_t)ROWS * HD * 4;
  __hip_bfloat16* hb    = (__hip_bfloat16*)(ws + off); off += (size_t)ROWS * HD * 2;
  float*          h1f   = (float*)(ws + off);          off += (size_t)ROWS * HD * 4;
  __hip_bfloat16* h1b   = (__hip_bfloat16*)(ws + off); off += (size_t)ROWS * HD * 2;
  float*          bufA  = (float*)(ws + off);          off += (size_t)ROWS * HD * 4;  // s / ffn2
  __hip_bfloat16* gb    = (__hip_bfloat16*)(ws + off); off += (size_t)ROWS * ID * 2;  // gelu out
  // retention buffer aliases d_out: fully rewritten by scan each layer, last
  // read is ln1; final LN overwrites d_out at the end. Saves 25 MB of ws.
  float*          bufB  = out;

  dim3 tb(32, 8);
  // ret_W: [L][K=HD][N=HD] -> [L][HD][HD]
  transpose_bf16_kernel<<<dim3(HD/32, HD/32, NL), tb, 0, stream>>>(retW, retWt, HD, HD);
  // W1: [L][K=HD][N=ID]
  transpose_bf16_kernel<<<dim3(ID/32, HD/32, NL), tb, 0, stream>>>(W1, W1t, HD, ID);
  // W2: [L][K=ID][N=HD]
  transpose_bf16_kernel<<<dim3(HD/32, ID/32, NL), tb, 0, stream>>>(W2, W2t, ID, HD);

  embed_ln_kernel<<<ROWS, 256, 0, stream>>>(ids, wemb, pemb, elns, elnb, hf, hb);

  for (int l = 0; l < NL; l++) {
    // s = sigmoid(h @ retW + rb)  -> bufA (f32)
    gemm_bt_kernel<1, 1, 0><<<dim3(ROWS/128, HD/64), 256, 0, stream>>>(
        hb, retWt + (size_t)l * HD * HD, retb + (size_t)l * HD,
        bufA, nullptr, ROWS, HD, HD);
    // retention scan -> bufB
    scan_kernel<<<NB * 16 * 3, 256, 0, stream>>>(bufA, bufB);
    // h1 = LN(h + retention)
    ln_kernel<1, 1><<<ROWS, 256, 0, stream>>>(hf, bufB,
        ln1s + (size_t)l * HD, ln1b + (size_t)l * HD, h1f, h1b);
    // g = gelu(h1 @ W1 + b1) -> gb (bf16 only)
    gemm_bt_kernel<2, 0, 1><<<dim3(ROWS/128, ID/64), 256, 0, stream>>>(
        h1b, W1t + (size_t)l * ID * HD, b1 + (size_t)l * ID,
        nullptr, gb, ROWS, ID, HD);
    // ffn2 = g @ W2 + b2 -> bufA (f32)
    gemm_bt_kernel<0, 1, 0><<<dim3(ROWS/128, HD/64), 256, 0, stream>>>(
        gb, W2t + (size_t)l * HD * ID, b2 + (size_t)l * HD,
        bufA, nullptr, ROWS, HD, ID);
    // h = LN(h1 + ffn2)
    ln_kernel<1, 1><<<ROWS, 256, 0, stream>>>(h1f, bufA,
        ln2s + (size_t)l * HD, ln2b + (size_t)l * HD, hf, hb);
  }
  // final LN -> d_out (f32 only)
  ln_kernel<0, 0><<<ROWS, 256, 0, stream>>>(hf, nullptr, fins, finb, out, nullptr);
}

// Round 3
// 861.868 us; speedup vs baseline: 1.1069x; 1.1069x over previous
//
#include <hip/hip_runtime.h>
#include <hip/hip_bf16.h>
#include <cstdint>
#include <cstddef>

// Problem dims
#define HD   768
#define ID   3072
#define NB   4
#define SL   2048
#define NL   4
#define ROWS (NB*SL)   // 8192

typedef __attribute__((ext_vector_type(8))) short bf16x8s;
typedef __attribute__((ext_vector_type(4))) float f32x4;

typedef __attribute__((address_space(1))) const unsigned int g_as1_u32;
typedef __attribute__((address_space(3))) unsigned int lds_as3_u32;

// async 16B/lane global->LDS copy (wave-uniform LDS base + lane*16)
__device__ __forceinline__ void gl2lds16(__hip_bfloat16* l, const __hip_bfloat16* g) {
  __builtin_amdgcn_global_load_lds((g_as1_u32*)g, (lds_as3_u32*)l, 16, 0, 0);
}

// ---------------------------------------------------------------------------
// LayerNorm body (row of 768, block of 256 threads, 3 elems/thread)
// ---------------------------------------------------------------------------
__device__ __forceinline__ void ln_body(float v[3], int tid,
    const float* __restrict__ scale, const float* __restrict__ bias,
    float* __restrict__ outf, __hip_bfloat16* __restrict__ outb,
    size_t rowoff, bool wb)
{
  __shared__ float red[8];
  float s = v[0] + v[1] + v[2];
#pragma unroll
  for (int off = 32; off; off >>= 1) s += __shfl_down(s, off);
  if ((tid & 63) == 0) red[tid >> 6] = s;
  __syncthreads();
  float mean = (red[0] + red[1] + red[2] + red[3]) * (1.0f / 768.0f);
  float q = 0.f;
#pragma unroll
  for (int i = 0; i < 3; i++) { float d = v[i] - mean; q += d * d; }
#pragma unroll
  for (int off = 32; off; off >>= 1) q += __shfl_down(q, off);
  if ((tid & 63) == 0) red[4 + (tid >> 6)] = q;
  __syncthreads();
  float rstd = rsqrtf((red[4] + red[5] + red[6] + red[7]) * (1.0f / 768.0f) + 1e-5f);
#pragma unroll
  for (int i = 0; i < 3; i++) {
    int j = tid + i * 256;
    float o = (v[i] - mean) * rstd * scale[j] + bias[j];
    outf[rowoff + j] = o;
    if (wb) outb[rowoff + j] = __float2bfloat16(o);
  }
}

// embedding gather + pos add + LN
__global__ __launch_bounds__(256) void embed_ln_kernel(
    const int* __restrict__ ids, const float* __restrict__ wemb,
    const float* __restrict__ pemb,
    const float* __restrict__ scale, const float* __restrict__ bias,
    float* __restrict__ outf, __hip_bfloat16* __restrict__ outb)
{
  int row = blockIdx.x;           // b*SL + t
  int t = row & (SL - 1);
  int id = ids[row];
  int tid = threadIdx.x;
  float v[3];
#pragma unroll
  for (int i = 0; i < 3; i++) {
    int j = tid + i * 256;
    v[i] = wemb[(size_t)id * HD + j] + pemb[(size_t)t * HD + j];
  }
  ln_body(v, tid, scale, bias, outf, outb, (size_t)row * HD, true);
}

// (optional residual add) + LN
template <int ADD, int WB>
__global__ __launch_bounds__(256) void ln_kernel(
    const float* __restrict__ x, const float* __restrict__ y,
    const float* __restrict__ scale, const float* __restrict__ bias,
    float* __restrict__ outf, __hip_bfloat16* __restrict__ outb)
{
  int row = blockIdx.x;
  int tid = threadIdx.x;
  const float* xr = x + (size_t)row * HD;
  const float* yr = y + (size_t)row * HD;
  float v[3];
#pragma unroll
  for (int i = 0; i < 3; i++) {
    int j = tid + i * 256;
    v[i] = xr[j];
    if (ADD) v[i] += yr[j];
  }
  ln_body(v, tid, scale, bias, outf, outb, (size_t)row * HD, WB != 0);
}

// ---------------------------------------------------------------------------
// Weight transpose + f32->bf16: in [K][N] f32 -> out [N][K] bf16, grid.z = layer
// ---------------------------------------------------------------------------
__global__ __launch_bounds__(256) void transpose_bf16_kernel(
    const float* __restrict__ in, __hip_bfloat16* __restrict__ out, int K, int N)
{
  __shared__ float tile[32][33];
  const float* inp = in + (size_t)blockIdx.z * K * N;
  __hip_bfloat16* outp = out + (size_t)blockIdx.z * K * N;
  int n0 = blockIdx.x * 32, k0 = blockIdx.y * 32;
  int tx = threadIdx.x, ty = threadIdx.y;   // (32, 8)
#pragma unroll
  for (int i = 0; i < 4; i++)
    tile[ty + i * 8][tx] = inp[(size_t)(k0 + ty + i * 8) * N + n0 + tx];
  __syncthreads();
#pragma unroll
  for (int i = 0; i < 4; i++)
    outp[(size_t)(n0 + ty + i * 8) * K + k0 + tx] = __float2bfloat16(tile[tx][ty + i * 8]);
}

// ---------------------------------------------------------------------------
// Retention decay scan: r_t = 0.5*s_t + 0.5*r_{t-1}. Chunked (128/chunk) with
// 64-step warm-up (0.5^64 ~ 5e-20 -> exact to fp32).
// ---------------------------------------------------------------------------
__global__ __launch_bounds__(256) void scan_kernel(
    const float* __restrict__ s, float* __restrict__ r)
{
  int bid = blockIdx.x;             // b*48 + chunk*3 + sub
  int sub = bid % 3;
  int chunk = (bid / 3) % 16;
  int b = bid / 48;
  int h = sub * 256 + threadIdx.x;
  int tstart = chunk * 128;
  int t0 = tstart - 64; if (t0 < 0) t0 = 0;
  const float* sp = s + (size_t)b * SL * HD + h;
  float* rp = r + (size_t)b * SL * HD + h;
  float acc = 0.f;
#pragma unroll 8
  for (int t = t0; t < tstart; ++t)
    acc = 0.5f * (sp[(size_t)t * HD] + acc);
#pragma unroll 8
  for (int t = tstart; t < tstart + 128; ++t) {
    acc = 0.5f * (sp[(size_t)t * HD] + acc);
    rp[(size_t)t * HD] = acc;
  }
}

// ---------------------------------------------------------------------------
// m97-structure GEMM: C[M,N] = act(A[M,K] @ Bt[N,K]^T + bias).
// BM=128, BN in {128,64}, BK=32. 256 threads = 4 waves in 2x2 (BN=128) each
// owning 64x64 (4x4 frags), or 2x2 with 64x32 (4x2 frags) for BN=64.
// Staging: global_load_lds 16B/lane into linear LDS (no VGPR round-trip).
// ACT: 0 none, 1 sigmoid, 2 gelu. WF: write f32 C. WB: write bf16 C.
// ---------------------------------------------------------------------------
template <int BN, int ACT, int WF, int WB>
__global__ __launch_bounds__(256) void gemm_mfma_kernel(
    const __hip_bfloat16* __restrict__ A,
    const __hip_bfloat16* __restrict__ Bt,
    const float* __restrict__ bias,
    float* __restrict__ Cf, __hip_bfloat16* __restrict__ Cb,
    int M, int N, int K)
{
  constexpr int NF = BN / 32;               // N-frags per wave: 4 or 2
  __shared__ __align__(16) __hip_bfloat16 As[128 * 32];
  __shared__ __align__(16) __hip_bfloat16 Bs[BN * 32];
  const int m0 = blockIdx.x * 128;
  const int n0 = blockIdx.y * BN;
  const int tid  = threadIdx.x;
  const int lane = tid & 63;
  const int w    = tid >> 6;                // wave 0..3
  const int wr   = w >> 1;                  // 0..1 (M half)
  const int wc   = w & 1;                   // 0..1 (N half)
  const int lr   = lane & 15;
  const int kg   = lane >> 4;               // 0..3

  f32x4 acc[4][NF];
#pragma unroll
  for (int i = 0; i < 4; i++)
#pragma unroll
    for (int j = 0; j < NF; j++) acc[i][j] = (f32x4){0.f, 0.f, 0.f, 0.f};

  // staging: wave w, lane l covers LDS byte w*1024 + l*16
  //   -> row w*16 + l/4 (64B rows), col element (l%4)*8
  const int srow = (w << 4) + (lane >> 2);
  const int scol = (lane & 3) << 3;
  const __hip_bfloat16* aS0 = A  + (size_t)(m0 + srow) * K + scol;
  const __hip_bfloat16* aS1 = A  + (size_t)(m0 + srow + 64) * K + scol;
  const __hip_bfloat16* bS0 = Bt + (size_t)(n0 + srow) * K + scol;
  const __hip_bfloat16* bS1 = Bt + (size_t)(n0 + srow + 64) * K + scol;
  __hip_bfloat16* lA0 = As + (w << 9);
  __hip_bfloat16* lA1 = As + 2048 + (w << 9);
  __hip_bfloat16* lB0 = Bs + (w << 9);
  __hip_bfloat16* lB1 = Bs + 2048 + (w << 9);

  for (int k0 = 0; k0 < K; k0 += 32) {
    __syncthreads();                        // prev-iter reads done
    gl2lds16(lA0, aS0 + k0);
    gl2lds16(lA1, aS1 + k0);
    gl2lds16(lB0, bS0 + k0);
    if constexpr (BN == 128) gl2lds16(lB1, bS1 + k0);
    __syncthreads();                        // staging complete (vmcnt drained)

    bf16x8s af[4], bq[NF];
#pragma unroll
    for (int i = 0; i < 4; i++)
      af[i] = *reinterpret_cast<const bf16x8s*>(&As[(wr * 64 + i * 16 + lr) * 32 + kg * 8]);
#pragma unroll
    for (int j = 0; j < NF; j++)
      bq[j] = *reinterpret_cast<const bf16x8s*>(&Bs[(wc * (BN / 2) + j * 16 + lr) * 32 + kg * 8]);
#pragma unroll
    for (int i = 0; i < 4; i++)
#pragma unroll
      for (int j = 0; j < NF; j++)
        acc[i][j] = __builtin_amdgcn_mfma_f32_16x16x32_bf16(af[i], bq[j], acc[i][j], 0, 0, 0);
  }

#pragma unroll
  for (int i = 0; i < 4; i++)
#pragma unroll
    for (int j = 0; j < NF; j++) {
      int col = n0 + wc * (BN / 2) + j * 16 + lr;
      float bv = bias[col];
#pragma unroll
      for (int r = 0; r < 4; r++) {
        int row = m0 + wr * 64 + i * 16 + kg * 4 + r;
        float v = acc[i][j][r] + bv;
        if (ACT == 1) v = 1.f / (1.f + __expf(-v));
        else if (ACT == 2) {
          // gelu(tanh approx) = x * sigmoid(2*0.79788456*(x + 0.044715 x^3))
          float x = v;
          float z = 1.5957691216057308f * (x + 0.044715f * x * x * x);
          v = x / (1.f + __expf(-z));
        }
        if (WF) Cf[(size_t)row * N + col] = v;
        if (WB) Cb[(size_t)row * N + col] = __float2bfloat16(v);
      }
    }
}

// ---------------------------------------------------------------------------
extern "C" void kernel_launch(void* const* d_in, const int* in_sizes, int n_in,
                              void* d_out, int out_size, void* d_ws, size_t ws_size,
                              hipStream_t stream)
{
  const int*   ids  = (const int*)d_in[0];
  const float* wemb = (const float*)d_in[1];
  const float* pemb = (const float*)d_in[2];
  const float* elns = (const float*)d_in[3];
  const float* elnb = (const float*)d_in[4];
  const float* retW = (const float*)d_in[5];
  const float* retb = (const float*)d_in[6];
  const float* ln1s = (const float*)d_in[7];
  const float* ln1b = (const float*)d_in[8];
  const float* W1   = (const float*)d_in[9];
  const float* b1   = (const float*)d_in[10];
  const float* W2   = (const float*)d_in[11];
  const float* b2   = (const float*)d_in[12];
  const float* ln2s = (const float*)d_in[13];
  const float* ln2b = (const float*)d_in[14];
  const float* fins = (const float*)d_in[15];
  const float* finb = (const float*)d_in[16];
  float* out = (float*)d_out;

  char* ws = (char*)d_ws;
  size_t off = 0;
  __hip_bfloat16* retWt = (__hip_bfloat16*)(ws + off); off += (size_t)NL * HD * HD * 2;
  __hip_bfloat16* W1t   = (__hip_bfloat16*)(ws + off); off += (size_t)NL * HD * ID * 2;
  __hip_bfloat16* W2t   = (__hip_bfloat16*)(ws + off); off += (size_t)NL * ID * HD * 2;
  float*          hf    = (float*)(ws + off);          off += (size_t)ROWS * HD * 4;
  __hip_bfloat16* hb    = (__hip_bfloat16*)(ws + off); off += (size_t)ROWS * HD * 2;
  float*          h1f   = (float*)(ws + off);          off += (size_t)ROWS * HD * 4;
  __hip_bfloat16* h1b   = (__hip_bfloat16*)(ws + off); off += (size_t)ROWS * HD * 2;
  float*          bufA  = (float*)(ws + off);          off += (size_t)ROWS * HD * 4;  // s / ffn2
  __hip_bfloat16* gb    = (__hip_bfloat16*)(ws + off); off += (size_t)ROWS * ID * 2;  // gelu out
  // retention buffer aliases d_out: fully rewritten by scan each layer, last
  // read is ln1; final LN overwrites d_out at the end.
  float*          bufB  = out;

  dim3 tb(32, 8);
  transpose_bf16_kernel<<<dim3(HD/32, HD/32, NL), tb, 0, stream>>>(retW, retWt, HD, HD);
  transpose_bf16_kernel<<<dim3(ID/32, HD/32, NL), tb, 0, stream>>>(W1, W1t, HD, ID);
  transpose_bf16_kernel<<<dim3(HD/32, ID/32, NL), tb, 0, stream>>>(W2, W2t, ID, HD);

  embed_ln_kernel<<<ROWS, 256, 0, stream>>>(ids, wemb, pemb, elns, elnb, hf, hb);

  for (int l = 0; l < NL; l++) {
    // s = sigmoid(h @ retW + rb) -> bufA (f32). N=768 -> BN=64 (768 blocks)
    gemm_mfma_kernel<64, 1, 1, 0><<<dim3(ROWS/128, HD/64), 256, 0, stream>>>(
        hb, retWt + (size_t)l * HD * HD, retb + (size_t)l * HD,
        bufA, nullptr, ROWS, HD, HD);
    // retention scan -> bufB
    scan_kernel<<<NB * 16 * 3, 256, 0, stream>>>(bufA, bufB);
    // h1 = LN(h + retention)
    ln_kernel<1, 1><<<ROWS, 256, 0, stream>>>(hf, bufB,
        ln1s + (size_t)l * HD, ln1b + (size_t)l * HD, h1f, h1b);
    // g = gelu(h1 @ W1 + b1) -> gb (bf16). N=3072 -> BN=128 (1536 blocks)
    gemm_mfma_kernel<128, 2, 0, 1><<<dim3(ROWS/128, ID/128), 256, 0, stream>>>(
        h1b, W1t + (size_t)l * ID * HD, b1 + (size_t)l * ID,
        nullptr, gb, ROWS, ID, HD);
    // ffn2 = g @ W2 + b2 -> bufA (f32). N=768 -> BN=64 (768 blocks)
    gemm_mfma_kernel<64, 0, 1, 0><<<dim3(ROWS/128, HD/64), 256, 0, stream>>>(
        gb, W2t + (size_t)l * HD * ID, b2 + (size_t)l * HD,
        bufA, nullptr, ROWS, HD, ID);
    // h = LN(h1 + ffn2)
    ln_kernel<1, 1><<<ROWS, 256, 0, stream>>>(h1f, bufA,
        ln2s + (size_t)l * HD, ln2b + (size_t)l * HD, hf, hb);
  }
  // final LN -> d_out (f32 only)
  ln_kernel<0, 0><<<ROWS, 256, 0, stream>>>(hf, nullptr, fins, finb, out, nullptr);
}

// Round 4
// 825.000 us; speedup vs baseline: 1.1564x; 1.0447x over previous
//
#include <hip/hip_runtime.h>
#include <hip/hip_bf16.h>
#include <cstdint>
#include <cstddef>

// Problem dims
#define HD   768
#define ID   3072
#define NB   4
#define SL   2048
#define NL   4
#define ROWS (NB*SL)   // 8192

typedef __attribute__((ext_vector_type(8))) short bf16x8s;
typedef __attribute__((ext_vector_type(4))) float f32x4;

typedef __attribute__((address_space(1))) const unsigned int g_as1_u32;
typedef __attribute__((address_space(3))) unsigned int lds_as3_u32;

// async 16B/lane global->LDS copy (wave-uniform LDS base + lane*16)
__device__ __forceinline__ void gl2lds16(__hip_bfloat16* l, const __hip_bfloat16* g) {
  __builtin_amdgcn_global_load_lds((g_as1_u32*)g, (lds_as3_u32*)l, 16, 0, 0);
}

// ---------------------------------------------------------------------------
// LayerNorm body (row of 768, block of 256 threads, 3 elems/thread)
// ---------------------------------------------------------------------------
__device__ __forceinline__ void ln_body(float v[3], int tid,
    const float* __restrict__ scale, const float* __restrict__ bias,
    float* __restrict__ outf, __hip_bfloat16* __restrict__ outb,
    size_t rowoff, bool wb)
{
  __shared__ float red[8];
  float s = v[0] + v[1] + v[2];
#pragma unroll
  for (int off = 32; off; off >>= 1) s += __shfl_down(s, off);
  if ((tid & 63) == 0) red[tid >> 6] = s;
  __syncthreads();
  float mean = (red[0] + red[1] + red[2] + red[3]) * (1.0f / 768.0f);
  float q = 0.f;
#pragma unroll
  for (int i = 0; i < 3; i++) { float d = v[i] - mean; q += d * d; }
#pragma unroll
  for (int off = 32; off; off >>= 1) q += __shfl_down(q, off);
  if ((tid & 63) == 0) red[4 + (tid >> 6)] = q;
  __syncthreads();
  float rstd = rsqrtf((red[4] + red[5] + red[6] + red[7]) * (1.0f / 768.0f) + 1e-5f);
#pragma unroll
  for (int i = 0; i < 3; i++) {
    int j = tid + i * 256;
    float o = (v[i] - mean) * rstd * scale[j] + bias[j];
    outf[rowoff + j] = o;
    if (wb) outb[rowoff + j] = __float2bfloat16(o);
  }
}

// embedding gather + pos add + LN
__global__ __launch_bounds__(256) void embed_ln_kernel(
    const int* __restrict__ ids, const float* __restrict__ wemb,
    const float* __restrict__ pemb,
    const float* __restrict__ scale, const float* __restrict__ bias,
    float* __restrict__ outf, __hip_bfloat16* __restrict__ outb)
{
  int row = blockIdx.x;           // b*SL + t
  int t = row & (SL - 1);
  int id = ids[row];
  int tid = threadIdx.x;
  float v[3];
#pragma unroll
  for (int i = 0; i < 3; i++) {
    int j = tid + i * 256;
    v[i] = wemb[(size_t)id * HD + j] + pemb[(size_t)t * HD + j];
  }
  ln_body(v, tid, scale, bias, outf, outb, (size_t)row * HD, true);
}

// (optional residual add) + LN
template <int ADD, int WB>
__global__ __launch_bounds__(256) void ln_kernel(
    const float* __restrict__ x, const float* __restrict__ y,
    const float* __restrict__ scale, const float* __restrict__ bias,
    float* __restrict__ outf, __hip_bfloat16* __restrict__ outb)
{
  int row = blockIdx.x;
  int tid = threadIdx.x;
  const float* xr = x + (size_t)row * HD;
  const float* yr = y + (size_t)row * HD;
  float v[3];
#pragma unroll
  for (int i = 0; i < 3; i++) {
    int j = tid + i * 256;
    v[i] = xr[j];
    if (ADD) v[i] += yr[j];
  }
  ln_body(v, tid, scale, bias, outf, outb, (size_t)row * HD, WB != 0);
}

// ---------------------------------------------------------------------------
// Weight transpose + f32->bf16: in [K][N] f32 -> out [N][K] bf16, grid.z = layer
// ---------------------------------------------------------------------------
__global__ __launch_bounds__(256) void transpose_bf16_kernel(
    const float* __restrict__ in, __hip_bfloat16* __restrict__ out, int K, int N)
{
  __shared__ float tile[32][33];
  const float* inp = in + (size_t)blockIdx.z * K * N;
  __hip_bfloat16* outp = out + (size_t)blockIdx.z * K * N;
  int n0 = blockIdx.x * 32, k0 = blockIdx.y * 32;
  int tx = threadIdx.x, ty = threadIdx.y;   // (32, 8)
#pragma unroll
  for (int i = 0; i < 4; i++)
    tile[ty + i * 8][tx] = inp[(size_t)(k0 + ty + i * 8) * N + n0 + tx];
  __syncthreads();
#pragma unroll
  for (int i = 0; i < 4; i++)
    outp[(size_t)(n0 + ty + i * 8) * K + k0 + tx] = __float2bfloat16(tile[tx][ty + i * 8]);
}

// ---------------------------------------------------------------------------
// Retention decay scan: r_t = 0.5*s_t + 0.5*r_{t-1}. Chunked (128/chunk) with
// 64-step warm-up (0.5^64 ~ 5e-20 -> exact to fp32). s is bf16.
// ---------------------------------------------------------------------------
__global__ __launch_bounds__(256) void scan_kernel(
    const __hip_bfloat16* __restrict__ s, float* __restrict__ r)
{
  int bid = blockIdx.x;             // b*48 + chunk*3 + sub
  int sub = bid % 3;
  int chunk = (bid / 3) % 16;
  int b = bid / 48;
  int h = sub * 256 + threadIdx.x;
  int tstart = chunk * 128;
  int t0 = tstart - 64; if (t0 < 0) t0 = 0;
  const __hip_bfloat16* sp = s + (size_t)b * SL * HD + h;
  float* rp = r + (size_t)b * SL * HD + h;
  float acc = 0.f;
#pragma unroll 8
  for (int t = t0; t < tstart; ++t)
    acc = 0.5f * (__bfloat162float(sp[(size_t)t * HD]) + acc);
#pragma unroll 8
  for (int t = tstart; t < tstart + 128; ++t) {
    acc = 0.5f * (__bfloat162float(sp[(size_t)t * HD]) + acc);
    rp[(size_t)t * HD] = acc;
  }
}

// ---------------------------------------------------------------------------
// m97-structure GEMM: C[M,N] = act(A[M,K] @ Bt[N,K]^T + bias).
// BM=128, BN in {128,96}, BK=32. 256 threads = 4 waves in 2x2, each owning
// 64 x BN/2 (4 x BN/32 frags of 16x16).
// Staging: global_load_lds 16B/lane into linear LDS (no VGPR round-trip).
// ACT: 0 none, 1 sigmoid, 2 gelu. WF: write f32 C. WB: write bf16 C.
// ---------------------------------------------------------------------------
template <int BN, int ACT, int WF, int WB>
__global__ __launch_bounds__(256) void gemm_mfma_kernel(
    const __hip_bfloat16* __restrict__ A,
    const __hip_bfloat16* __restrict__ Bt,
    const float* __restrict__ bias,
    float* __restrict__ Cf, __hip_bfloat16* __restrict__ Cb,
    int M, int N, int K)
{
  constexpr int NF = BN / 32;               // N-frags per wave: 4 or 3
  __shared__ __align__(16) __hip_bfloat16 As[128 * 32];
  __shared__ __align__(16) __hip_bfloat16 Bs[BN * 32];
  const int m0 = blockIdx.x * 128;
  const int n0 = blockIdx.y * BN;
  const int tid  = threadIdx.x;
  const int lane = tid & 63;
  const int w    = tid >> 6;                // wave 0..3
  const int wr   = w >> 1;                  // 0..1 (M half)
  const int wc   = w & 1;                   // 0..1 (N half)
  const int lr   = lane & 15;
  const int kg   = lane >> 4;               // 0..3

  f32x4 acc[4][NF];
#pragma unroll
  for (int i = 0; i < 4; i++)
#pragma unroll
    for (int j = 0; j < NF; j++) acc[i][j] = (f32x4){0.f, 0.f, 0.f, 0.f};

  // staging: wave w, lane l covers LDS byte w*1024 + l*16
  //   -> row w*16 + l/4 (64B rows), col element (l%4)*8
  const int srow = (w << 4) + (lane >> 2);
  const int scol = (lane & 3) << 3;
  const __hip_bfloat16* aS0 = A  + (size_t)(m0 + srow) * K + scol;
  const __hip_bfloat16* aS1 = A  + (size_t)(m0 + srow + 64) * K + scol;
  const __hip_bfloat16* bS0 = Bt + (size_t)(n0 + srow) * K + scol;
  const __hip_bfloat16* bS1 = Bt + (size_t)(n0 + srow + 64) * K + scol;
  __hip_bfloat16* lA0 = As + (w << 9);
  __hip_bfloat16* lA1 = As + 2048 + (w << 9);
  __hip_bfloat16* lB0 = Bs + (w << 9);
  __hip_bfloat16* lB1 = Bs + 2048 + (w << 9);

  for (int k0 = 0; k0 < K; k0 += 32) {
    __syncthreads();                        // prev-iter reads done
    gl2lds16(lA0, aS0 + k0);
    gl2lds16(lA1, aS1 + k0);
    gl2lds16(lB0, bS0 + k0);
    if constexpr (BN == 128) {
      gl2lds16(lB1, bS1 + k0);
    } else if constexpr (BN == 96) {
      if (w < 2) gl2lds16(lB1, bS1 + k0);   // rows 64..95 (2KB, waves 0-1)
    }
    __syncthreads();                        // staging complete (vmcnt drained)

    bf16x8s af[4], bq[NF];
#pragma unroll
    for (int i = 0; i < 4; i++)
      af[i] = *reinterpret_cast<const bf16x8s*>(&As[(wr * 64 + i * 16 + lr) * 32 + kg * 8]);
#pragma unroll
    for (int j = 0; j < NF; j++)
      bq[j] = *reinterpret_cast<const bf16x8s*>(&Bs[(wc * (BN / 2) + j * 16 + lr) * 32 + kg * 8]);
#pragma unroll
    for (int i = 0; i < 4; i++)
#pragma unroll
      for (int j = 0; j < NF; j++)
        acc[i][j] = __builtin_amdgcn_mfma_f32_16x16x32_bf16(af[i], bq[j], acc[i][j], 0, 0, 0);
  }

#pragma unroll
  for (int i = 0; i < 4; i++)
#pragma unroll
    for (int j = 0; j < NF; j++) {
      int col = n0 + wc * (BN / 2) + j * 16 + lr;
      float bv = bias[col];
#pragma unroll
      for (int r = 0; r < 4; r++) {
        int row = m0 + wr * 64 + i * 16 + kg * 4 + r;
        float v = acc[i][j][r] + bv;
        if (ACT == 1) v = 1.f / (1.f + __expf(-v));
        else if (ACT == 2) {
          // gelu(tanh approx) = x * sigmoid(2*0.79788456*(x + 0.044715 x^3))
          float x = v;
          float z = 1.5957691216057308f * (x + 0.044715f * x * x * x);
          v = x / (1.f + __expf(-z));
        }
        if (WF) Cf[(size_t)row * N + col] = v;
        if (WB) Cb[(size_t)row * N + col] = __float2bfloat16(v);
      }
    }
}

// ---------------------------------------------------------------------------
extern "C" void kernel_launch(void* const* d_in, const int* in_sizes, int n_in,
                              void* d_out, int out_size, void* d_ws, size_t ws_size,
                              hipStream_t stream)
{
  const int*   ids  = (const int*)d_in[0];
  const float* wemb = (const float*)d_in[1];
  const float* pemb = (const float*)d_in[2];
  const float* elns = (const float*)d_in[3];
  const float* elnb = (const float*)d_in[4];
  const float* retW = (const float*)d_in[5];
  const float* retb = (const float*)d_in[6];
  const float* ln1s = (const float*)d_in[7];
  const float* ln1b = (const float*)d_in[8];
  const float* W1   = (const float*)d_in[9];
  const float* b1   = (const float*)d_in[10];
  const float* W2   = (const float*)d_in[11];
  const float* b2   = (const float*)d_in[12];
  const float* ln2s = (const float*)d_in[13];
  const float* ln2b = (const float*)d_in[14];
  const float* fins = (const float*)d_in[15];
  const float* finb = (const float*)d_in[16];
  float* out = (float*)d_out;

  char* ws = (char*)d_ws;
  size_t off = 0;
  __hip_bfloat16* retWt = (__hip_bfloat16*)(ws + off); off += (size_t)NL * HD * HD * 2;
  __hip_bfloat16* W1t   = (__hip_bfloat16*)(ws + off); off += (size_t)NL * HD * ID * 2;
  __hip_bfloat16* W2t   = (__hip_bfloat16*)(ws + off); off += (size_t)NL * ID * HD * 2;
  float*          hf    = (float*)(ws + off);          off += (size_t)ROWS * HD * 4;
  __hip_bfloat16* hb    = (__hip_bfloat16*)(ws + off); off += (size_t)ROWS * HD * 2;
  float*          h1f   = (float*)(ws + off);          off += (size_t)ROWS * HD * 4;
  __hip_bfloat16* h1b   = (__hip_bfloat16*)(ws + off); off += (size_t)ROWS * HD * 2;
  float*          bufA  = (float*)(ws + off);          off += (size_t)ROWS * HD * 4;  // ffn2
  __hip_bfloat16* gb    = (__hip_bfloat16*)(ws + off); off += (size_t)ROWS * ID * 2;  // s / gelu out
  // retention buffer aliases d_out: fully rewritten by scan each layer, last
  // read is ln1; final LN overwrites d_out at the end.
  float*          bufB  = out;
  // sigmoid output s (bf16) aliases gb: scan consumes it before FFN1 rewrites gb.
  __hip_bfloat16* sb    = gb;

  dim3 tb(32, 8);
  transpose_bf16_kernel<<<dim3(HD/32, HD/32, NL), tb, 0, stream>>>(retW, retWt, HD, HD);
  transpose_bf16_kernel<<<dim3(ID/32, HD/32, NL), tb, 0, stream>>>(W1, W1t, HD, ID);
  transpose_bf16_kernel<<<dim3(HD/32, ID/32, NL), tb, 0, stream>>>(W2, W2t, ID, HD);

  embed_ln_kernel<<<ROWS, 256, 0, stream>>>(ids, wemb, pemb, elns, elnb, hf, hb);

  for (int l = 0; l < NL; l++) {
    // s = sigmoid(h @ retW + rb) -> sb (bf16). N=768 -> BN=96 (512 blocks)
    gemm_mfma_kernel<96, 1, 0, 1><<<dim3(ROWS/128, HD/96), 256, 0, stream>>>(
        hb, retWt + (size_t)l * HD * HD, retb + (size_t)l * HD,
        nullptr, sb, ROWS, HD, HD);
    // retention scan -> bufB (f32)
    scan_kernel<<<NB * 16 * 3, 256, 0, stream>>>(sb, bufB);
    // h1 = LN(h + retention)
    ln_kernel<1, 1><<<ROWS, 256, 0, stream>>>(hf, bufB,
        ln1s + (size_t)l * HD, ln1b + (size_t)l * HD, h1f, h1b);
    // g = gelu(h1 @ W1 + b1) -> gb (bf16). N=3072 -> BN=128 (1536 blocks)
    gemm_mfma_kernel<128, 2, 0, 1><<<dim3(ROWS/128, ID/128), 256, 0, stream>>>(
        h1b, W1t + (size_t)l * ID * HD, b1 + (size_t)l * ID,
        nullptr, gb, ROWS, ID, HD);
    // ffn2 = g @ W2 + b2 -> bufA (f32). N=768 -> BN=96 (512 blocks)
    gemm_mfma_kernel<96, 0, 1, 0><<<dim3(ROWS/128, HD/96), 256, 0, stream>>>(
        gb, W2t + (size_t)l * HD * ID, b2 + (size_t)l * HD,
        bufA, nullptr, ROWS, HD, ID);
    // h = LN(h1 + ffn2)
    ln_kernel<1, 1><<<ROWS, 256, 0, stream>>>(h1f, bufA,
        ln2s + (size_t)l * HD, ln2b + (size_t)l * HD, hf, hb);
  }
  // final LN -> d_out (f32 only)
  ln_kernel<0, 0><<<ROWS, 256, 0, stream>>>(hf, nullptr, fins, finb, out, nullptr);
}

// Round 5
// 749.495 us; speedup vs baseline: 1.2729x; 1.1007x over previous
//
#include <hip/hip_runtime.h>
#include <hip/hip_bf16.h>
#include <cstdint>
#include <cstddef>

// Problem dims
#define HD   768
#define ID   3072
#define NB   4
#define SL   2048
#define NL   4
#define ROWS (NB*SL)   // 8192

typedef __attribute__((ext_vector_type(8))) short bf16x8s;
typedef __attribute__((ext_vector_type(4))) float f32x4;
typedef __attribute__((ext_vector_type(4))) unsigned short u16x4;

typedef __attribute__((address_space(1))) const unsigned int g_as1_u32;
typedef __attribute__((address_space(3))) unsigned int lds_as3_u32;

// async 16B/lane global->LDS copy (wave-uniform LDS base + lane*16)
__device__ __forceinline__ void gl2lds16(__hip_bfloat16* l, const __hip_bfloat16* g) {
  __builtin_amdgcn_global_load_lds((g_as1_u32*)g, (lds_as3_u32*)l, 16, 0, 0);
}

__device__ __forceinline__ float bfu2f(unsigned short u) {
  return __uint_as_float((unsigned int)u << 16);
}
__device__ __forceinline__ unsigned short f2bfu(float f) {
  __hip_bfloat16 h = __float2bfloat16(f);
  return *reinterpret_cast<unsigned short*>(&h);
}

// ---------------------------------------------------------------------------
// Wave-per-row LayerNorm: block=256 (4 waves), wave w does row blockIdx*4+w.
// 12 elems/lane, shfl_xor reduce, no __syncthreads.
// OUTF32: write f32 (final LN) else bf16.
// ---------------------------------------------------------------------------
template <int OUTF32>
__global__ __launch_bounds__(256) void ln_row_kernel(
    const __hip_bfloat16* __restrict__ x,
    const float* __restrict__ scale, const float* __restrict__ bias,
    __hip_bfloat16* __restrict__ ob, float* __restrict__ of)
{
  const int w = threadIdx.x >> 6, lane = threadIdx.x & 63;
  const size_t row = (size_t)blockIdx.x * 4 + w;
  const __hip_bfloat16* xr = x + row * HD;
  float v[12];
#pragma unroll
  for (int c = 0; c < 3; c++) {
    u16x4 u = *reinterpret_cast<const u16x4*>(xr + c * 256 + lane * 4);
#pragma unroll
    for (int i = 0; i < 4; i++) v[c * 4 + i] = bfu2f(u[i]);
  }
  float s = 0.f;
#pragma unroll
  for (int i = 0; i < 12; i++) s += v[i];
#pragma unroll
  for (int m = 1; m < 64; m <<= 1) s += __shfl_xor(s, m);
  float mean = s * (1.0f / 768.0f);
  float q = 0.f;
#pragma unroll
  for (int i = 0; i < 12; i++) { float d = v[i] - mean; q += d * d; }
#pragma unroll
  for (int m = 1; m < 64; m <<= 1) q += __shfl_xor(q, m);
  float rstd = rsqrtf(q * (1.0f / 768.0f) + 1e-5f);
#pragma unroll
  for (int c = 0; c < 3; c++) {
    int j0 = c * 256 + lane * 4;
    if (OUTF32) {
      f32x4 o;
#pragma unroll
      for (int i = 0; i < 4; i++)
        o[i] = (v[c * 4 + i] - mean) * rstd * scale[j0 + i] + bias[j0 + i];
      *reinterpret_cast<f32x4*>(of + row * HD + j0) = o;
    } else {
      u16x4 o;
#pragma unroll
      for (int i = 0; i < 4; i++)
        o[i] = f2bfu((v[c * 4 + i] - mean) * rstd * scale[j0 + i] + bias[j0 + i]);
      *reinterpret_cast<u16x4*>(ob + row * HD + j0) = o;
    }
  }
}

// embedding gather + pos add + LN (wave-per-row), writes bf16
__global__ __launch_bounds__(256) void embed_ln_kernel(
    const int* __restrict__ ids, const float* __restrict__ wemb,
    const float* __restrict__ pemb,
    const float* __restrict__ scale, const float* __restrict__ bias,
    __hip_bfloat16* __restrict__ ob)
{
  const int w = threadIdx.x >> 6, lane = threadIdx.x & 63;
  const size_t row = (size_t)blockIdx.x * 4 + w;
  const int t = (int)(row & (SL - 1));
  const int id = ids[row];
  float v[12];
#pragma unroll
  for (int c = 0; c < 3; c++) {
    int j0 = c * 256 + lane * 4;
    f32x4 a = *reinterpret_cast<const f32x4*>(wemb + (size_t)id * HD + j0);
    f32x4 p = *reinterpret_cast<const f32x4*>(pemb + (size_t)t * HD + j0);
#pragma unroll
    for (int i = 0; i < 4; i++) v[c * 4 + i] = a[i] + p[i];
  }
  float s = 0.f;
#pragma unroll
  for (int i = 0; i < 12; i++) s += v[i];
#pragma unroll
  for (int m = 1; m < 64; m <<= 1) s += __shfl_xor(s, m);
  float mean = s * (1.0f / 768.0f);
  float q = 0.f;
#pragma unroll
  for (int i = 0; i < 12; i++) { float d = v[i] - mean; q += d * d; }
#pragma unroll
  for (int m = 1; m < 64; m <<= 1) q += __shfl_xor(q, m);
  float rstd = rsqrtf(q * (1.0f / 768.0f) + 1e-5f);
#pragma unroll
  for (int c = 0; c < 3; c++) {
    int j0 = c * 256 + lane * 4;
    u16x4 o;
#pragma unroll
    for (int i = 0; i < 4; i++)
      o[i] = f2bfu((v[c * 4 + i] - mean) * rstd * scale[j0 + i] + bias[j0 + i]);
    *reinterpret_cast<u16x4*>(ob + row * HD + j0) = o;
  }
}

// ---------------------------------------------------------------------------
// Weight transpose + f32->bf16: in [K][N] f32 -> out [N][K] bf16, grid.z = layer
// ---------------------------------------------------------------------------
__global__ __launch_bounds__(256) void transpose_bf16_kernel(
    const float* __restrict__ in, __hip_bfloat16* __restrict__ out, int K, int N)
{
  __shared__ float tile[32][33];
  const float* inp = in + (size_t)blockIdx.z * K * N;
  __hip_bfloat16* outp = out + (size_t)blockIdx.z * K * N;
  int n0 = blockIdx.x * 32, k0 = blockIdx.y * 32;
  int tx = threadIdx.x, ty = threadIdx.y;   // (32, 8)
#pragma unroll
  for (int i = 0; i < 4; i++)
    tile[ty + i * 8][tx] = inp[(size_t)(k0 + ty + i * 8) * N + n0 + tx];
  __syncthreads();
#pragma unroll
  for (int i = 0; i < 4; i++)
    outp[(size_t)(n0 + ty + i * 8) * K + k0 + tx] = __float2bfloat16(tile[tx][ty + i * 8]);
}

// ---------------------------------------------------------------------------
// Retention scan + residual fuse: r_t = 0.5*s_t + 0.5*r_{t-1};
// writes z = h + r (bf16). 128-chunk with 64-step warm-up (exact to fp32).
// ---------------------------------------------------------------------------
__global__ __launch_bounds__(256) void scan_kernel(
    const __hip_bfloat16* __restrict__ s,
    const __hip_bfloat16* __restrict__ h,
    __hip_bfloat16* __restrict__ z)
{
  int bid = blockIdx.x;             // b*48 + chunk*3 + sub
  int sub = bid % 3;
  int chunk = (bid / 3) % 16;
  int b = bid / 48;
  int hh = sub * 256 + threadIdx.x;
  int tstart = chunk * 128;
  int t0 = tstart - 64; if (t0 < 0) t0 = 0;
  const __hip_bfloat16* sp = s + (size_t)b * SL * HD + hh;
  const __hip_bfloat16* hp = h + (size_t)b * SL * HD + hh;
  __hip_bfloat16* zp = z + (size_t)b * SL * HD + hh;
  float acc = 0.f;
#pragma unroll 8
  for (int t = t0; t < tstart; ++t)
    acc = 0.5f * (__bfloat162float(sp[(size_t)t * HD]) + acc);
#pragma unroll 8
  for (int t = tstart; t < tstart + 128; ++t) {
    acc = 0.5f * (__bfloat162float(sp[(size_t)t * HD]) + acc);
    zp[(size_t)t * HD] = __float2bfloat16(acc + __bfloat162float(hp[(size_t)t * HD]));
  }
}

// ---------------------------------------------------------------------------
// m97-structure GEMM: C[M,N] = act(A[M,K] @ Bt[N,K]^T + bias) [+ R], bf16 out.
// BM=128, BN in {128,96}, BK=32. 4 waves in 2x2, each 64 x BN/2.
// ACT: 0 none, 1 sigmoid, 2 gelu. RADD: add residual R (bf16) before store.
// ---------------------------------------------------------------------------
template <int BN, int ACT, int RADD>
__global__ __launch_bounds__(256) void gemm_mfma_kernel(
    const __hip_bfloat16* __restrict__ A,
    const __hip_bfloat16* __restrict__ Bt,
    const float* __restrict__ bias,
    const __hip_bfloat16* __restrict__ R,
    __hip_bfloat16* __restrict__ Cb,
    int M, int N, int K)
{
  constexpr int NF = BN / 32;               // N-frags per wave: 4 or 3
  __shared__ __align__(16) __hip_bfloat16 As[128 * 32];
  __shared__ __align__(16) __hip_bfloat16 Bs[BN * 32];
  const int m0 = blockIdx.x * 128;
  const int n0 = blockIdx.y * BN;
  const int tid  = threadIdx.x;
  const int lane = tid & 63;
  const int w    = tid >> 6;                // wave 0..3
  const int wr   = w >> 1;                  // 0..1 (M half)
  const int wc   = w & 1;                   // 0..1 (N half)
  const int lr   = lane & 15;
  const int kg   = lane >> 4;               // 0..3

  f32x4 acc[4][NF];
#pragma unroll
  for (int i = 0; i < 4; i++)
#pragma unroll
    for (int j = 0; j < NF; j++) acc[i][j] = (f32x4){0.f, 0.f, 0.f, 0.f};

  // staging: wave w, lane l covers LDS byte w*1024 + l*16
  const int srow = (w << 4) + (lane >> 2);
  const int scol = (lane & 3) << 3;
  const __hip_bfloat16* aS0 = A  + (size_t)(m0 + srow) * K + scol;
  const __hip_bfloat16* aS1 = A  + (size_t)(m0 + srow + 64) * K + scol;
  const __hip_bfloat16* bS0 = Bt + (size_t)(n0 + srow) * K + scol;
  const __hip_bfloat16* bS1 = Bt + (size_t)(n0 + srow + 64) * K + scol;
  __hip_bfloat16* lA0 = As + (w << 9);
  __hip_bfloat16* lA1 = As + 2048 + (w << 9);
  __hip_bfloat16* lB0 = Bs + (w << 9);
  __hip_bfloat16* lB1 = Bs + 2048 + (w << 9);

  for (int k0 = 0; k0 < K; k0 += 32) {
    __syncthreads();                        // prev-iter reads done
    gl2lds16(lA0, aS0 + k0);
    gl2lds16(lA1, aS1 + k0);
    gl2lds16(lB0, bS0 + k0);
    if constexpr (BN == 128) {
      gl2lds16(lB1, bS1 + k0);
    } else if constexpr (BN == 96) {
      if (w < 2) gl2lds16(lB1, bS1 + k0);   // rows 64..95 (waves 0-1)
    }
    __syncthreads();                        // staging complete (vmcnt drained)

    bf16x8s af[4], bq[NF];
#pragma unroll
    for (int i = 0; i < 4; i++)
      af[i] = *reinterpret_cast<const bf16x8s*>(&As[(wr * 64 + i * 16 + lr) * 32 + kg * 8]);
#pragma unroll
    for (int j = 0; j < NF; j++)
      bq[j] = *reinterpret_cast<const bf16x8s*>(&Bs[(wc * (BN / 2) + j * 16 + lr) * 32 + kg * 8]);
#pragma unroll
    for (int i = 0; i < 4; i++)
#pragma unroll
      for (int j = 0; j < NF; j++)
        acc[i][j] = __builtin_amdgcn_mfma_f32_16x16x32_bf16(af[i], bq[j], acc[i][j], 0, 0, 0);
  }

#pragma unroll
  for (int i = 0; i < 4; i++)
#pragma unroll
    for (int j = 0; j < NF; j++) {
      int col = n0 + wc * (BN / 2) + j * 16 + lr;
      float bv = bias[col];
#pragma unroll
      for (int r = 0; r < 4; r++) {
        int row = m0 + wr * 64 + i * 16 + kg * 4 + r;
        float v = acc[i][j][r] + bv;
        if (ACT == 1) v = 1.f / (1.f + __expf(-v));
        else if (ACT == 2) {
          float x = v;
          float z = 1.5957691216057308f * (x + 0.044715f * x * x * x);
          v = x / (1.f + __expf(-z));
        }
        if (RADD) v += __bfloat162float(R[(size_t)row * N + col]);
        Cb[(size_t)row * N + col] = __float2bfloat16(v);
      }
    }
}

// ---------------------------------------------------------------------------
extern "C" void kernel_launch(void* const* d_in, const int* in_sizes, int n_in,
                              void* d_out, int out_size, void* d_ws, size_t ws_size,
                              hipStream_t stream)
{
  const int*   ids  = (const int*)d_in[0];
  const float* wemb = (const float*)d_in[1];
  const float* pemb = (const float*)d_in[2];
  const float* elns = (const float*)d_in[3];
  const float* elnb = (const float*)d_in[4];
  const float* retW = (const float*)d_in[5];
  const float* retb = (const float*)d_in[6];
  const float* ln1s = (const float*)d_in[7];
  const float* ln1b = (const float*)d_in[8];
  const float* W1   = (const float*)d_in[9];
  const float* b1   = (const float*)d_in[10];
  const float* W2   = (const float*)d_in[11];
  const float* b2   = (const float*)d_in[12];
  const float* ln2s = (const float*)d_in[13];
  const float* ln2b = (const float*)d_in[14];
  const float* fins = (const float*)d_in[15];
  const float* finb = (const float*)d_in[16];
  float* out = (float*)d_out;

  char* ws = (char*)d_ws;
  size_t off = 0;
  __hip_bfloat16* retWt = (__hip_bfloat16*)(ws + off); off += (size_t)NL * HD * HD * 2;
  __hip_bfloat16* W1t   = (__hip_bfloat16*)(ws + off); off += (size_t)NL * HD * ID * 2;
  __hip_bfloat16* W2t   = (__hip_bfloat16*)(ws + off); off += (size_t)NL * ID * HD * 2;
  __hip_bfloat16* hb    = (__hip_bfloat16*)(ws + off); off += (size_t)ROWS * HD * 2;  // residual h
  __hip_bfloat16* h1b   = (__hip_bfloat16*)(ws + off); off += (size_t)ROWS * HD * 2;  // h1
  __hip_bfloat16* zb    = (__hip_bfloat16*)(ws + off); off += (size_t)ROWS * HD * 2;  // h+r / h1+ffn2
  __hip_bfloat16* gb    = (__hip_bfloat16*)(ws + off); off += (size_t)ROWS * ID * 2;  // s / gelu out
  // sigmoid output s aliases gb (scan consumes s before FFN1 rewrites gb);
  // yb (= h1+ffn2) aliases zb (ln1 consumes z before FFN2 writes yb).
  __hip_bfloat16* sb = gb;
  __hip_bfloat16* yb = zb;

  dim3 tb(32, 8);
  transpose_bf16_kernel<<<dim3(HD/32, HD/32, NL), tb, 0, stream>>>(retW, retWt, HD, HD);
  transpose_bf16_kernel<<<dim3(ID/32, HD/32, NL), tb, 0, stream>>>(W1, W1t, HD, ID);
  transpose_bf16_kernel<<<dim3(HD/32, ID/32, NL), tb, 0, stream>>>(W2, W2t, ID, HD);

  embed_ln_kernel<<<ROWS/4, 256, 0, stream>>>(ids, wemb, pemb, elns, elnb, hb);

  for (int l = 0; l < NL; l++) {
    // s = sigmoid(h @ retW + rb) -> sb (bf16). BN=96 (512 blocks)
    gemm_mfma_kernel<96, 1, 0><<<dim3(ROWS/128, HD/96), 256, 0, stream>>>(
        hb, retWt + (size_t)l * HD * HD, retb + (size_t)l * HD,
        nullptr, sb, ROWS, HD, HD);
    // z = h + retention(s) -> zb (bf16)
    scan_kernel<<<NB * 16 * 3, 256, 0, stream>>>(sb, hb, zb);
    // h1 = LN(z)
    ln_row_kernel<0><<<ROWS/4, 256, 0, stream>>>(zb,
        ln1s + (size_t)l * HD, ln1b + (size_t)l * HD, h1b, nullptr);
    // g = gelu(h1 @ W1 + b1) -> gb (bf16). BN=128 (1536 blocks)
    gemm_mfma_kernel<128, 2, 0><<<dim3(ROWS/128, ID/128), 256, 0, stream>>>(
        h1b, W1t + (size_t)l * ID * HD, b1 + (size_t)l * ID,
        nullptr, gb, ROWS, ID, HD);
    // y = h1 + (g @ W2 + b2) -> yb (bf16). BN=96 (512 blocks)
    gemm_mfma_kernel<96, 0, 1><<<dim3(ROWS/128, HD/96), 256, 0, stream>>>(
        gb, W2t + (size_t)l * HD * ID, b2 + (size_t)l * HD,
        h1b, yb, ROWS, HD, ID);
    // h = LN(y)
    ln_row_kernel<0><<<ROWS/4, 256, 0, stream>>>(yb,
        ln2s + (size_t)l * HD, ln2b + (size_t)l * HD, hb, nullptr);
  }
  // final LN -> d_out (f32)
  ln_row_kernel<1><<<ROWS/4, 256, 0, stream>>>(hb, fins, finb, nullptr, out);
}

// Round 6
// 664.831 us; speedup vs baseline: 1.4350x; 1.1273x over previous
//
#include <hip/hip_runtime.h>
#include <hip/hip_bf16.h>
#include <cstdint>
#include <cstddef>

// Problem dims
#define HD   768
#define ID   3072
#define NB   4
#define SL   2048
#define NL   4
#define ROWS (NB*SL)   // 8192

typedef __attribute__((ext_vector_type(8))) short bf16x8s;
typedef __attribute__((ext_vector_type(4))) float f32x4;
typedef __attribute__((ext_vector_type(4))) unsigned short u16x4;

typedef __attribute__((address_space(1))) const unsigned int g_as1_u32;
typedef __attribute__((address_space(3))) unsigned int lds_as3_u32;

// async 16B/lane global->LDS copy (wave-uniform LDS base + lane*16)
__device__ __forceinline__ void gl2lds16(__hip_bfloat16* l, const __hip_bfloat16* g) {
  __builtin_amdgcn_global_load_lds((g_as1_u32*)g, (lds_as3_u32*)l, 16, 0, 0);
}

__device__ __forceinline__ float bfu2f(unsigned short u) {
  return __uint_as_float((unsigned int)u << 16);
}
__device__ __forceinline__ unsigned short f2bfu(float f) {
  __hip_bfloat16 h = __float2bfloat16(f);
  return *reinterpret_cast<unsigned short*>(&h);
}

// ---------------------------------------------------------------------------
// Wave-per-row LayerNorm: block=256 (4 waves), wave w does row blockIdx*4+w.
// 12 elems/lane, shfl_xor reduce, no __syncthreads.
// ---------------------------------------------------------------------------
template <int OUTF32>
__global__ __launch_bounds__(256) void ln_row_kernel(
    const __hip_bfloat16* __restrict__ x,
    const float* __restrict__ scale, const float* __restrict__ bias,
    __hip_bfloat16* __restrict__ ob, float* __restrict__ of)
{
  const int w = threadIdx.x >> 6, lane = threadIdx.x & 63;
  const size_t row = (size_t)blockIdx.x * 4 + w;
  const __hip_bfloat16* xr = x + row * HD;
  float v[12];
#pragma unroll
  for (int c = 0; c < 3; c++) {
    u16x4 u = *reinterpret_cast<const u16x4*>(xr + c * 256 + lane * 4);
#pragma unroll
    for (int i = 0; i < 4; i++) v[c * 4 + i] = bfu2f(u[i]);
  }
  float s = 0.f;
#pragma unroll
  for (int i = 0; i < 12; i++) s += v[i];
#pragma unroll
  for (int m = 1; m < 64; m <<= 1) s += __shfl_xor(s, m);
  float mean = s * (1.0f / 768.0f);
  float q = 0.f;
#pragma unroll
  for (int i = 0; i < 12; i++) { float d = v[i] - mean; q += d * d; }
#pragma unroll
  for (int m = 1; m < 64; m <<= 1) q += __shfl_xor(q, m);
  float rstd = rsqrtf(q * (1.0f / 768.0f) + 1e-5f);
#pragma unroll
  for (int c = 0; c < 3; c++) {
    int j0 = c * 256 + lane * 4;
    if (OUTF32) {
      f32x4 o;
#pragma unroll
      for (int i = 0; i < 4; i++)
        o[i] = (v[c * 4 + i] - mean) * rstd * scale[j0 + i] + bias[j0 + i];
      *reinterpret_cast<f32x4*>(of + row * HD + j0) = o;
    } else {
      u16x4 o;
#pragma unroll
      for (int i = 0; i < 4; i++)
        o[i] = f2bfu((v[c * 4 + i] - mean) * rstd * scale[j0 + i] + bias[j0 + i]);
      *reinterpret_cast<u16x4*>(ob + row * HD + j0) = o;
    }
  }
}

// embedding gather + pos add + LN (wave-per-row), writes bf16
__global__ __launch_bounds__(256) void embed_ln_kernel(
    const int* __restrict__ ids, const float* __restrict__ wemb,
    const float* __restrict__ pemb,
    const float* __restrict__ scale, const float* __restrict__ bias,
    __hip_bfloat16* __restrict__ ob)
{
  const int w = threadIdx.x >> 6, lane = threadIdx.x & 63;
  const size_t row = (size_t)blockIdx.x * 4 + w;
  const int t = (int)(row & (SL - 1));
  const int id = ids[row];
  float v[12];
#pragma unroll
  for (int c = 0; c < 3; c++) {
    int j0 = c * 256 + lane * 4;
    f32x4 a = *reinterpret_cast<const f32x4*>(wemb + (size_t)id * HD + j0);
    f32x4 p = *reinterpret_cast<const f32x4*>(pemb + (size_t)t * HD + j0);
#pragma unroll
    for (int i = 0; i < 4; i++) v[c * 4 + i] = a[i] + p[i];
  }
  float s = 0.f;
#pragma unroll
  for (int i = 0; i < 12; i++) s += v[i];
#pragma unroll
  for (int m = 1; m < 64; m <<= 1) s += __shfl_xor(s, m);
  float mean = s * (1.0f / 768.0f);
  float q = 0.f;
#pragma unroll
  for (int i = 0; i < 12; i++) { float d = v[i] - mean; q += d * d; }
#pragma unroll
  for (int m = 1; m < 64; m <<= 1) q += __shfl_xor(q, m);
  float rstd = rsqrtf(q * (1.0f / 768.0f) + 1e-5f);
#pragma unroll
  for (int c = 0; c < 3; c++) {
    int j0 = c * 256 + lane * 4;
    u16x4 o;
#pragma unroll
    for (int i = 0; i < 4; i++)
      o[i] = f2bfu((v[c * 4 + i] - mean) * rstd * scale[j0 + i] + bias[j0 + i]);
    *reinterpret_cast<u16x4*>(ob + row * HD + j0) = o;
  }
}

// ---------------------------------------------------------------------------
// Weight transpose + f32->bf16: in [K][N] f32 -> out [N][K] bf16, grid.z = layer
// ---------------------------------------------------------------------------
__global__ __launch_bounds__(256) void transpose_bf16_kernel(
    const float* __restrict__ in, __hip_bfloat16* __restrict__ out, int K, int N)
{
  __shared__ float tile[32][33];
  const float* inp = in + (size_t)blockIdx.z * K * N;
  __hip_bfloat16* outp = out + (size_t)blockIdx.z * K * N;
  int n0 = blockIdx.x * 32, k0 = blockIdx.y * 32;
  int tx = threadIdx.x, ty = threadIdx.y;   // (32, 8)
#pragma unroll
  for (int i = 0; i < 4; i++)
    tile[ty + i * 8][tx] = inp[(size_t)(k0 + ty + i * 8) * N + n0 + tx];
  __syncthreads();
#pragma unroll
  for (int i = 0; i < 4; i++)
    outp[(size_t)(n0 + ty + i * 8) * K + k0 + tx] = __float2bfloat16(tile[tx][ty + i * 8]);
}

// ---------------------------------------------------------------------------
// Retention scan + residual fuse: r_t = 0.5*s_t + 0.5*r_{t-1};
// writes z = h + r (bf16). 64-chunk with 64-step warm-up (0.5^64 -> exact).
// grid = NB * 32chunks * 3sub = 384 blocks x 256 threads (1536 waves).
// ---------------------------------------------------------------------------
__global__ __launch_bounds__(256) void scan_kernel(
    const __hip_bfloat16* __restrict__ s,
    const __hip_bfloat16* __restrict__ h,
    __hip_bfloat16* __restrict__ z)
{
  int bid = blockIdx.x;             // b*96 + chunk*3 + sub
  int sub = bid % 3;
  int chunk = (bid / 3) % 32;
  int b = bid / 96;
  int hh = sub * 256 + threadIdx.x;
  int tstart = chunk * 64;
  int t0 = tstart - 64; if (t0 < 0) t0 = 0;
  const __hip_bfloat16* sp = s + (size_t)b * SL * HD + hh;
  const __hip_bfloat16* hp = h + (size_t)b * SL * HD + hh;
  __hip_bfloat16* zp = z + (size_t)b * SL * HD + hh;
  float acc = 0.f;
#pragma unroll 8
  for (int t = t0; t < tstart; ++t)
    acc = 0.5f * (__bfloat162float(sp[(size_t)t * HD]) + acc);
#pragma unroll 8
  for (int t = tstart; t < tstart + 64; ++t) {
    acc = 0.5f * (__bfloat162float(sp[(size_t)t * HD]) + acc);
    zp[(size_t)t * HD] = __float2bfloat16(acc + __bfloat162float(hp[(size_t)t * HD]));
  }
}

// ---------------------------------------------------------------------------
// m97-structure GEMM, BK=64 as 2 packed BK=32 subtiles (half the barriers).
// C[M,N] = act(A[M,K] @ Bt[N,K]^T + bias) [+ R], bf16 out.
// BM=128, BN in {128,96}. 4 waves in 2x2, each 64 x BN/2.
// LDS: As[2][128][32], Bs[2][BN][32] linear (conflict-free ds_read_b128).
// ACT: 0 none, 1 sigmoid, 2 gelu. RADD: add residual R (bf16) before store.
// ---------------------------------------------------------------------------
template <int BN, int ACT, int RADD>
__global__ __launch_bounds__(256) void gemm_mfma_kernel(
    const __hip_bfloat16* __restrict__ A,
    const __hip_bfloat16* __restrict__ Bt,
    const float* __restrict__ bias,
    const __hip_bfloat16* __restrict__ R,
    __hip_bfloat16* __restrict__ Cb,
    int M, int N, int K)
{
  constexpr int NF = BN / 32;               // N-frags per wave: 4 or 3
  constexpr int BSTRIDE = BN * 32;          // Bs subtile stride (elems)
  __shared__ __align__(16) __hip_bfloat16 As[2 * 128 * 32];
  __shared__ __align__(16) __hip_bfloat16 Bs[2 * BSTRIDE];
  const int m0 = blockIdx.x * 128;
  const int n0 = blockIdx.y * BN;
  const int tid  = threadIdx.x;
  const int lane = tid & 63;
  const int w    = tid >> 6;                // wave 0..3
  const int wr   = w >> 1;                  // 0..1 (M half)
  const int wc   = w & 1;                   // 0..1 (N half)
  const int lr   = lane & 15;
  const int kg   = lane >> 4;               // 0..3

  f32x4 acc[4][NF];
#pragma unroll
  for (int i = 0; i < 4; i++)
#pragma unroll
    for (int j = 0; j < NF; j++) acc[i][j] = (f32x4){0.f, 0.f, 0.f, 0.f};

  // staging: pass covers 64 rows x 32 k-elems (4 KB); wave w does 16 rows.
  // thread t -> row (w*16 + lane/4), k-slot (lane%4)*8
  const int srow = (w << 4) + (lane >> 2);
  const int scol = (lane & 3) << 3;
  const __hip_bfloat16* aS = A  + (size_t)(m0 + srow) * K + scol;
  const __hip_bfloat16* bS = Bt + (size_t)(n0 + srow) * K + scol;
  const size_t K64 = (size_t)64 * K;
  __hip_bfloat16* lw = (__hip_bfloat16*)0;  // silence unused warn path

  for (int k0 = 0; k0 < K; k0 += 64) {
    __syncthreads();                        // prev-iter LDS reads drained
    // A: 4 passes (kk 0/1 x row-half 0/1)
    gl2lds16(As + (w << 9),                aS + k0);              // kk0 rows 0-63
    gl2lds16(As + 2048 + (w << 9),         aS + k0 + K64);        // kk0 rows 64-127
    gl2lds16(As + 4096 + (w << 9),         aS + k0 + 32);         // kk1 rows 0-63
    gl2lds16(As + 4096 + 2048 + (w << 9),  aS + k0 + K64 + 32);   // kk1 rows 64-127
    // B
    gl2lds16(Bs + (w << 9),                bS + k0);              // kk0 rows 0-63
    gl2lds16(Bs + BSTRIDE + (w << 9),      bS + k0 + 32);         // kk1 rows 0-63
    if constexpr (BN == 128) {
      gl2lds16(Bs + 2048 + (w << 9),            bS + k0 + K64);       // kk0 rows 64-127
      gl2lds16(Bs + BSTRIDE + 2048 + (w << 9),  bS + k0 + K64 + 32);  // kk1 rows 64-127
    } else if constexpr (BN == 96) {
      if (w < 2) {                                                 // rows 64-95
        gl2lds16(Bs + 2048 + (w << 9),           bS + k0 + K64);
        gl2lds16(Bs + BSTRIDE + 2048 + (w << 9), bS + k0 + K64 + 32);
      }
    }
    __syncthreads();                        // staging complete (vmcnt drained)

#pragma unroll
    for (int kk = 0; kk < 2; kk++) {
      bf16x8s af[4], bq[NF];
#pragma unroll
      for (int i = 0; i < 4; i++)
        af[i] = *reinterpret_cast<const bf16x8s*>(
            &As[kk * 4096 + (wr * 64 + i * 16 + lr) * 32 + kg * 8]);
#pragma unroll
      for (int j = 0; j < NF; j++)
        bq[j] = *reinterpret_cast<const bf16x8s*>(
            &Bs[kk * BSTRIDE + (wc * (BN / 2) + j * 16 + lr) * 32 + kg * 8]);
#pragma unroll
      for (int i = 0; i < 4; i++)
#pragma unroll
        for (int j = 0; j < NF; j++)
          acc[i][j] = __builtin_amdgcn_mfma_f32_16x16x32_bf16(af[i], bq[j], acc[i][j], 0, 0, 0);
    }
  }
  (void)lw;

#pragma unroll
  for (int i = 0; i < 4; i++)
#pragma unroll
    for (int j = 0; j < NF; j++) {
      int col = n0 + wc * (BN / 2) + j * 16 + lr;
      float bv = bias[col];
#pragma unroll
      for (int r = 0; r < 4; r++) {
        int row = m0 + wr * 64 + i * 16 + kg * 4 + r;
        float v = acc[i][j][r] + bv;
        if (ACT == 1) v = 1.f / (1.f + __expf(-v));
        else if (ACT == 2) {
          float x = v;
          float z = 1.5957691216057308f * (x + 0.044715f * x * x * x);
          v = x / (1.f + __expf(-z));
        }
        if (RADD) v += __bfloat162float(R[(size_t)row * N + col]);
        Cb[(size_t)row * N + col] = __float2bfloat16(v);
      }
    }
}

// ---------------------------------------------------------------------------
extern "C" void kernel_launch(void* const* d_in, const int* in_sizes, int n_in,
                              void* d_out, int out_size, void* d_ws, size_t ws_size,
                              hipStream_t stream)
{
  const int*   ids  = (const int*)d_in[0];
  const float* wemb = (const float*)d_in[1];
  const float* pemb = (const float*)d_in[2];
  const float* elns = (const float*)d_in[3];
  const float* elnb = (const float*)d_in[4];
  const float* retW = (const float*)d_in[5];
  const float* retb = (const float*)d_in[6];
  const float* ln1s = (const float*)d_in[7];
  const float* ln1b = (const float*)d_in[8];
  const float* W1   = (const float*)d_in[9];
  const float* b1   = (const float*)d_in[10];
  const float* W2   = (const float*)d_in[11];
  const float* b2   = (const float*)d_in[12];
  const float* ln2s = (const float*)d_in[13];
  const float* ln2b = (const float*)d_in[14];
  const float* fins = (const float*)d_in[15];
  const float* finb = (const float*)d_in[16];
  float* out = (float*)d_out;

  char* ws = (char*)d_ws;
  size_t off = 0;
  __hip_bfloat16* retWt = (__hip_bfloat16*)(ws + off); off += (size_t)NL * HD * HD * 2;
  __hip_bfloat16* W1t   = (__hip_bfloat16*)(ws + off); off += (size_t)NL * HD * ID * 2;
  __hip_bfloat16* W2t   = (__hip_bfloat16*)(ws + off); off += (size_t)NL * ID * HD * 2;
  __hip_bfloat16* hb    = (__hip_bfloat16*)(ws + off); off += (size_t)ROWS * HD * 2;  // residual h
  __hip_bfloat16* h1b   = (__hip_bfloat16*)(ws + off); off += (size_t)ROWS * HD * 2;  // h1
  __hip_bfloat16* zb    = (__hip_bfloat16*)(ws + off); off += (size_t)ROWS * HD * 2;  // h+r / h1+ffn2
  __hip_bfloat16* gb    = (__hip_bfloat16*)(ws + off); off += (size_t)ROWS * ID * 2;  // s / gelu out
  // sigmoid output s aliases gb (scan consumes s before FFN1 rewrites gb);
  // yb (= h1+ffn2) aliases zb (ln1 consumes z before FFN2 writes yb).
  __hip_bfloat16* sb = gb;
  __hip_bfloat16* yb = zb;

  dim3 tb(32, 8);
  transpose_bf16_kernel<<<dim3(HD/32, HD/32, NL), tb, 0, stream>>>(retW, retWt, HD, HD);
  transpose_bf16_kernel<<<dim3(ID/32, HD/32, NL), tb, 0, stream>>>(W1, W1t, HD, ID);
  transpose_bf16_kernel<<<dim3(HD/32, ID/32, NL), tb, 0, stream>>>(W2, W2t, ID, HD);

  embed_ln_kernel<<<ROWS/4, 256, 0, stream>>>(ids, wemb, pemb, elns, elnb, hb);

  for (int l = 0; l < NL; l++) {
    // s = sigmoid(h @ retW + rb) -> sb (bf16). BN=96 (512 blocks)
    gemm_mfma_kernel<96, 1, 0><<<dim3(ROWS/128, HD/96), 256, 0, stream>>>(
        hb, retWt + (size_t)l * HD * HD, retb + (size_t)l * HD,
        nullptr, sb, ROWS, HD, HD);
    // z = h + retention(s) -> zb (bf16)
    scan_kernel<<<NB * 32 * 3, 256, 0, stream>>>(sb, hb, zb);
    // h1 = LN(z)
    ln_row_kernel<0><<<ROWS/4, 256, 0, stream>>>(zb,
        ln1s + (size_t)l * HD, ln1b + (size_t)l * HD, h1b, nullptr);
    // g = gelu(h1 @ W1 + b1) -> gb (bf16). BN=128 (1536 blocks)
    gemm_mfma_kernel<128, 2, 0><<<dim3(ROWS/128, ID/128), 256, 0, stream>>>(
        h1b, W1t + (size_t)l * ID * HD, b1 + (size_t)l * ID,
        nullptr, gb, ROWS, ID, HD);
    // y = h1 + (g @ W2 + b2) -> yb (bf16). BN=96 (512 blocks)
    gemm_mfma_kernel<96, 0, 1><<<dim3(ROWS/128, HD/96), 256, 0, stream>>>(
        gb, W2t + (size_t)l * HD * ID, b2 + (size_t)l * HD,
        h1b, yb, ROWS, HD, ID);
    // h = LN(y)
    ln_row_kernel<0><<<ROWS/4, 256, 0, stream>>>(yb,
        ln2s + (size_t)l * HD, ln2b + (size_t)l * HD, hb, nullptr);
  }
  // final LN -> d_out (f32)
  ln_row_kernel<1><<<ROWS/4, 256, 0, stream>>>(hb, fins, finb, nullptr, out);
}

// Round 7
// 621.468 us; speedup vs baseline: 1.5351x; 1.0698x over previous
//
#include <hip/hip_runtime.h>
#include <hip/hip_bf16.h>
#include <cstdint>
#include <cstddef>

// Problem dims
#define HD   768
#define ID   3072
#define NB   4
#define SL   2048
#define NL   4
#define ROWS (NB*SL)   // 8192

typedef __attribute__((ext_vector_type(8))) short bf16x8s;
typedef __attribute__((ext_vector_type(4))) float f32x4;
typedef __attribute__((ext_vector_type(4))) unsigned short u16x4;

typedef __attribute__((address_space(1))) const unsigned int g_as1_u32;
typedef __attribute__((address_space(3))) unsigned int lds_as3_u32;

// async 16B/lane global->LDS copy (wave-uniform LDS base + lane*16)
__device__ __forceinline__ void gl2lds16(__hip_bfloat16* l, const __hip_bfloat16* g) {
  __builtin_amdgcn_global_load_lds((g_as1_u32*)g, (lds_as3_u32*)l, 16, 0, 0);
}

__device__ __forceinline__ float bfu2f(unsigned short u) {
  return __uint_as_float((unsigned int)u << 16);
}
__device__ __forceinline__ unsigned short f2bfu(float f) {
  __hip_bfloat16 h = __float2bfloat16(f);
  return *reinterpret_cast<unsigned short*>(&h);
}

// ---------------------------------------------------------------------------
// Wave-per-row LayerNorm: block=256 (4 waves), wave w does row blockIdx*4+w.
// 12 elems/lane, shfl_xor reduce, no __syncthreads.
// ---------------------------------------------------------------------------
template <int OUTF32>
__global__ __launch_bounds__(256) void ln_row_kernel(
    const __hip_bfloat16* __restrict__ x,
    const float* __restrict__ scale, const float* __restrict__ bias,
    __hip_bfloat16* __restrict__ ob, float* __restrict__ of)
{
  const int w = threadIdx.x >> 6, lane = threadIdx.x & 63;
  const size_t row = (size_t)blockIdx.x * 4 + w;
  const __hip_bfloat16* xr = x + row * HD;
  float v[12];
#pragma unroll
  for (int c = 0; c < 3; c++) {
    u16x4 u = *reinterpret_cast<const u16x4*>(xr + c * 256 + lane * 4);
#pragma unroll
    for (int i = 0; i < 4; i++) v[c * 4 + i] = bfu2f(u[i]);
  }
  float s = 0.f;
#pragma unroll
  for (int i = 0; i < 12; i++) s += v[i];
#pragma unroll
  for (int m = 1; m < 64; m <<= 1) s += __shfl_xor(s, m);
  float mean = s * (1.0f / 768.0f);
  float q = 0.f;
#pragma unroll
  for (int i = 0; i < 12; i++) { float d = v[i] - mean; q += d * d; }
#pragma unroll
  for (int m = 1; m < 64; m <<= 1) q += __shfl_xor(q, m);
  float rstd = rsqrtf(q * (1.0f / 768.0f) + 1e-5f);
#pragma unroll
  for (int c = 0; c < 3; c++) {
    int j0 = c * 256 + lane * 4;
    if (OUTF32) {
      f32x4 o;
#pragma unroll
      for (int i = 0; i < 4; i++)
        o[i] = (v[c * 4 + i] - mean) * rstd * scale[j0 + i] + bias[j0 + i];
      *reinterpret_cast<f32x4*>(of + row * HD + j0) = o;
    } else {
      u16x4 o;
#pragma unroll
      for (int i = 0; i < 4; i++)
        o[i] = f2bfu((v[c * 4 + i] - mean) * rstd * scale[j0 + i] + bias[j0 + i]);
      *reinterpret_cast<u16x4*>(ob + row * HD + j0) = o;
    }
  }
}

// embedding gather + pos add + LN (wave-per-row), writes bf16
__global__ __launch_bounds__(256) void embed_ln_kernel(
    const int* __restrict__ ids, const float* __restrict__ wemb,
    const float* __restrict__ pemb,
    const float* __restrict__ scale, const float* __restrict__ bias,
    __hip_bfloat16* __restrict__ ob)
{
  const int w = threadIdx.x >> 6, lane = threadIdx.x & 63;
  const size_t row = (size_t)blockIdx.x * 4 + w;
  const int t = (int)(row & (SL - 1));
  const int id = ids[row];
  float v[12];
#pragma unroll
  for (int c = 0; c < 3; c++) {
    int j0 = c * 256 + lane * 4;
    f32x4 a = *reinterpret_cast<const f32x4*>(wemb + (size_t)id * HD + j0);
    f32x4 p = *reinterpret_cast<const f32x4*>(pemb + (size_t)t * HD + j0);
#pragma unroll
    for (int i = 0; i < 4; i++) v[c * 4 + i] = a[i] + p[i];
  }
  float s = 0.f;
#pragma unroll
  for (int i = 0; i < 12; i++) s += v[i];
#pragma unroll
  for (int m = 1; m < 64; m <<= 1) s += __shfl_xor(s, m);
  float mean = s * (1.0f / 768.0f);
  float q = 0.f;
#pragma unroll
  for (int i = 0; i < 12; i++) { float d = v[i] - mean; q += d * d; }
#pragma unroll
  for (int m = 1; m < 64; m <<= 1) q += __shfl_xor(q, m);
  float rstd = rsqrtf(q * (1.0f / 768.0f) + 1e-5f);
#pragma unroll
  for (int c = 0; c < 3; c++) {
    int j0 = c * 256 + lane * 4;
    u16x4 o;
#pragma unroll
    for (int i = 0; i < 4; i++)
      o[i] = f2bfu((v[c * 4 + i] - mean) * rstd * scale[j0 + i] + bias[j0 + i]);
    *reinterpret_cast<u16x4*>(ob + row * HD + j0) = o;
  }
}

// ---------------------------------------------------------------------------
// Weight transpose + f32->bf16: in [K][N] f32 -> out [N][K] bf16, grid.z = layer
// ---------------------------------------------------------------------------
__global__ __launch_bounds__(256) void transpose_bf16_kernel(
    const float* __restrict__ in, __hip_bfloat16* __restrict__ out, int K, int N)
{
  __shared__ float tile[32][33];
  const float* inp = in + (size_t)blockIdx.z * K * N;
  __hip_bfloat16* outp = out + (size_t)blockIdx.z * K * N;
  int n0 = blockIdx.x * 32, k0 = blockIdx.y * 32;
  int tx = threadIdx.x, ty = threadIdx.y;   // (32, 8)
#pragma unroll
  for (int i = 0; i < 4; i++)
    tile[ty + i * 8][tx] = inp[(size_t)(k0 + ty + i * 8) * N + n0 + tx];
  __syncthreads();
#pragma unroll
  for (int i = 0; i < 4; i++)
    outp[(size_t)(n0 + ty + i * 8) * K + k0 + tx] = __float2bfloat16(tile[tx][ty + i * 8]);
}

// ---------------------------------------------------------------------------
// Retention scan + residual fuse: r_t = 0.5*s_t + 0.5*r_{t-1};
// writes z = h + r (bf16). 64-chunk with 64-step warm-up (0.5^64 -> exact).
// ---------------------------------------------------------------------------
__global__ __launch_bounds__(256) void scan_kernel(
    const __hip_bfloat16* __restrict__ s,
    const __hip_bfloat16* __restrict__ h,
    __hip_bfloat16* __restrict__ z)
{
  int bid = blockIdx.x;             // b*96 + chunk*3 + sub
  int sub = bid % 3;
  int chunk = (bid / 3) % 32;
  int b = bid / 96;
  int hh = sub * 256 + threadIdx.x;
  int tstart = chunk * 64;
  int t0 = tstart - 64; if (t0 < 0) t0 = 0;
  const __hip_bfloat16* sp = s + (size_t)b * SL * HD + hh;
  const __hip_bfloat16* hp = h + (size_t)b * SL * HD + hh;
  __hip_bfloat16* zp = z + (size_t)b * SL * HD + hh;
  float acc = 0.f;
#pragma unroll 8
  for (int t = t0; t < tstart; ++t)
    acc = 0.5f * (__bfloat162float(sp[(size_t)t * HD]) + acc);
#pragma unroll 8
  for (int t = tstart; t < tstart + 64; ++t) {
    acc = 0.5f * (__bfloat162float(sp[(size_t)t * HD]) + acc);
    zp[(size_t)t * HD] = __float2bfloat16(acc + __bfloat162float(hp[(size_t)t * HD]));
  }
}

// ---------------------------------------------------------------------------
// 2-phase double-buffered MFMA GEMM (T3-minimum schedule):
//   prologue: stage(buf0, tile0); barrier;
//   iter t:   stage(buf^1, tile t+1)  [loads in flight across compute]
//             ds_read + MFMA on buf   [overlap]
//             barrier                  [single drain point per tile]
// C[M,N] = act(A[M,K] @ Bt[N,K]^T + bias) [+ R], bf16 out.
// BM=128, BN in {128,96}, BK=64 (2 packed 32-K subtiles per buffer).
// LDS: 2 x (As[2][128][32] + Bs[2][BN][32]) = 64/56 KB -> 2 blocks/CU.
// ---------------------------------------------------------------------------
template <int BN, int ACT, int RADD>
__global__ __launch_bounds__(256) void gemm_mfma_kernel(
    const __hip_bfloat16* __restrict__ A,
    const __hip_bfloat16* __restrict__ Bt,
    const float* __restrict__ bias,
    const __hip_bfloat16* __restrict__ R,
    __hip_bfloat16* __restrict__ Cb,
    int M, int N, int K)
{
  constexpr int NF = BN / 32;               // N-frags per wave: 4 or 3
  constexpr int BSTRIDE = BN * 32;          // Bs kk-subtile stride (elems)
  constexpr int ABUF = 2 * 128 * 32;        // As per-buffer elems (8192)
  constexpr int BBUF = 2 * BSTRIDE;         // Bs per-buffer elems
  __shared__ __align__(16) __hip_bfloat16 As[2 * ABUF];
  __shared__ __align__(16) __hip_bfloat16 Bs[2 * BBUF];
  const int m0 = blockIdx.x * 128;
  const int n0 = blockIdx.y * BN;
  const int tid  = threadIdx.x;
  const int lane = tid & 63;
  const int w    = tid >> 6;                // wave 0..3
  const int wr   = w >> 1;                  // 0..1 (M half)
  const int wc   = w & 1;                   // 0..1 (N half)
  const int lr   = lane & 15;
  const int kg   = lane >> 4;               // 0..3

  f32x4 acc[4][NF];
#pragma unroll
  for (int i = 0; i < 4; i++)
#pragma unroll
    for (int j = 0; j < NF; j++) acc[i][j] = (f32x4){0.f, 0.f, 0.f, 0.f};

  // staging: pass covers 64 rows x 32 k-elems (4 KB); wave w does 16 rows.
  const int srow = (w << 4) + (lane >> 2);
  const int scol = (lane & 3) << 3;
  const __hip_bfloat16* aS = A  + (size_t)(m0 + srow) * K + scol;
  const __hip_bfloat16* bS = Bt + (size_t)(n0 + srow) * K + scol;
  const size_t K64 = (size_t)64 * K;

  auto stage = [&](int buf, int k0) {
    __hip_bfloat16* Ab = As + buf * ABUF;
    __hip_bfloat16* Bb = Bs + buf * BBUF;
    gl2lds16(Ab + (w << 9),               aS + k0);              // kk0 rows 0-63
    gl2lds16(Ab + 2048 + (w << 9),        aS + k0 + K64);        // kk0 rows 64-127
    gl2lds16(Ab + 4096 + (w << 9),        aS + k0 + 32);         // kk1 rows 0-63
    gl2lds16(Ab + 4096 + 2048 + (w << 9), aS + k0 + K64 + 32);   // kk1 rows 64-127
    gl2lds16(Bb + (w << 9),               bS + k0);              // kk0 rows 0-63
    gl2lds16(Bb + BSTRIDE + (w << 9),     bS + k0 + 32);         // kk1 rows 0-63
    if constexpr (BN == 128) {
      gl2lds16(Bb + 2048 + (w << 9),            bS + k0 + K64);
      gl2lds16(Bb + BSTRIDE + 2048 + (w << 9),  bS + k0 + K64 + 32);
    } else if constexpr (BN == 96) {
      if (w < 2) {                                               // rows 64-95
        gl2lds16(Bb + 2048 + (w << 9),           bS + k0 + K64);
        gl2lds16(Bb + BSTRIDE + 2048 + (w << 9), bS + k0 + K64 + 32);
      }
    }
  };

  const int nt = K >> 6;                    // BK=64 tiles
  stage(0, 0);
  __syncthreads();                          // prologue drain

  for (int t = 0; t < nt; ++t) {
    const int cur = t & 1;
    if (t + 1 < nt) stage(cur ^ 1, (t + 1) << 6);  // prefetch next tile

    const __hip_bfloat16* Ab = As + cur * ABUF;
    const __hip_bfloat16* Bb = Bs + cur * BBUF;
#pragma unroll
    for (int kk = 0; kk < 2; kk++) {
      bf16x8s af[4], bq[NF];
#pragma unroll
      for (int i = 0; i < 4; i++)
        af[i] = *reinterpret_cast<const bf16x8s*>(
            &Ab[kk * 4096 + (wr * 64 + i * 16 + lr) * 32 + kg * 8]);
#pragma unroll
      for (int j = 0; j < NF; j++)
        bq[j] = *reinterpret_cast<const bf16x8s*>(
            &Bb[kk * BSTRIDE + (wc * (BN / 2) + j * 16 + lr) * 32 + kg * 8]);
#pragma unroll
      for (int i = 0; i < 4; i++)
#pragma unroll
        for (int j = 0; j < NF; j++)
          acc[i][j] = __builtin_amdgcn_mfma_f32_16x16x32_bf16(af[i], bq[j], acc[i][j], 0, 0, 0);
    }
    __syncthreads();                        // single drain: stage(t+1) + reads(t)
  }

#pragma unroll
  for (int i = 0; i < 4; i++)
#pragma unroll
    for (int j = 0; j < NF; j++) {
      int col = n0 + wc * (BN / 2) + j * 16 + lr;
      float bv = bias[col];
#pragma unroll
      for (int r = 0; r < 4; r++) {
        int row = m0 + wr * 64 + i * 16 + kg * 4 + r;
        float v = acc[i][j][r] + bv;
        if (ACT == 1) v = 1.f / (1.f + __expf(-v));
        else if (ACT == 2) {
          float x = v;
          float z = 1.5957691216057308f * (x + 0.044715f * x * x * x);
          v = x / (1.f + __expf(-z));
        }
        if (RADD) v += __bfloat162float(R[(size_t)row * N + col]);
        Cb[(size_t)row * N + col] = __float2bfloat16(v);
      }
    }
}

// ---------------------------------------------------------------------------
extern "C" void kernel_launch(void* const* d_in, const int* in_sizes, int n_in,
                              void* d_out, int out_size, void* d_ws, size_t ws_size,
                              hipStream_t stream)
{
  const int*   ids  = (const int*)d_in[0];
  const float* wemb = (const float*)d_in[1];
  const float* pemb = (const float*)d_in[2];
  const float* elns = (const float*)d_in[3];
  const float* elnb = (const float*)d_in[4];
  const float* retW = (const float*)d_in[5];
  const float* retb = (const float*)d_in[6];
  const float* ln1s = (const float*)d_in[7];
  const float* ln1b = (const float*)d_in[8];
  const float* W1   = (const float*)d_in[9];
  const float* b1   = (const float*)d_in[10];
  const float* W2   = (const float*)d_in[11];
  const float* b2   = (const float*)d_in[12];
  const float* ln2s = (const float*)d_in[13];
  const float* ln2b = (const float*)d_in[14];
  const float* fins = (const float*)d_in[15];
  const float* finb = (const float*)d_in[16];
  float* out = (float*)d_out;

  char* ws = (char*)d_ws;
  size_t off = 0;
  __hip_bfloat16* retWt = (__hip_bfloat16*)(ws + off); off += (size_t)NL * HD * HD * 2;
  __hip_bfloat16* W1t   = (__hip_bfloat16*)(ws + off); off += (size_t)NL * HD * ID * 2;
  __hip_bfloat16* W2t   = (__hip_bfloat16*)(ws + off); off += (size_t)NL * ID * HD * 2;
  __hip_bfloat16* hb    = (__hip_bfloat16*)(ws + off); off += (size_t)ROWS * HD * 2;  // residual h
  __hip_bfloat16* h1b   = (__hip_bfloat16*)(ws + off); off += (size_t)ROWS * HD * 2;  // h1
  __hip_bfloat16* zb    = (__hip_bfloat16*)(ws + off); off += (size_t)ROWS * HD * 2;  // h+r / h1+ffn2
  __hip_bfloat16* gb    = (__hip_bfloat16*)(ws + off); off += (size_t)ROWS * ID * 2;  // s / gelu out
  __hip_bfloat16* sb = gb;
  __hip_bfloat16* yb = zb;

  dim3 tb(32, 8);
  transpose_bf16_kernel<<<dim3(HD/32, HD/32, NL), tb, 0, stream>>>(retW, retWt, HD, HD);
  transpose_bf16_kernel<<<dim3(ID/32, HD/32, NL), tb, 0, stream>>>(W1, W1t, HD, ID);
  transpose_bf16_kernel<<<dim3(HD/32, ID/32, NL), tb, 0, stream>>>(W2, W2t, ID, HD);

  embed_ln_kernel<<<ROWS/4, 256, 0, stream>>>(ids, wemb, pemb, elns, elnb, hb);

  for (int l = 0; l < NL; l++) {
    // s = sigmoid(h @ retW + rb) -> sb (bf16). BN=96 (512 blocks)
    gemm_mfma_kernel<96, 1, 0><<<dim3(ROWS/128, HD/96), 256, 0, stream>>>(
        hb, retWt + (size_t)l * HD * HD, retb + (size_t)l * HD,
        nullptr, sb, ROWS, HD, HD);
    // z = h + retention(s) -> zb (bf16)
    scan_kernel<<<NB * 32 * 3, 256, 0, stream>>>(sb, hb, zb);
    // h1 = LN(z)
    ln_row_kernel<0><<<ROWS/4, 256, 0, stream>>>(zb,
        ln1s + (size_t)l * HD, ln1b + (size_t)l * HD, h1b, nullptr);
    // g = gelu(h1 @ W1 + b1) -> gb (bf16). BN=128 (1536 blocks)
    gemm_mfma_kernel<128, 2, 0><<<dim3(ROWS/128, ID/128), 256, 0, stream>>>(
        h1b, W1t + (size_t)l * ID * HD, b1 + (size_t)l * ID,
        nullptr, gb, ROWS, ID, HD);
    // y = h1 + (g @ W2 + b2) -> yb (bf16). BN=96 (512 blocks)
    gemm_mfma_kernel<96, 0, 1><<<dim3(ROWS/128, HD/96), 256, 0, stream>>>(
        gb, W2t + (size_t)l * HD * ID, b2 + (size_t)l * HD,
        h1b, yb, ROWS, HD, ID);
    // h = LN(y)
    ln_row_kernel<0><<<ROWS/4, 256, 0, stream>>>(yb,
        ln2s + (size_t)l * HD, ln2b + (size_t)l * HD, hb, nullptr);
  }
  // final LN -> d_out (f32)
  ln_row_kernel<1><<<ROWS/4, 256, 0, stream>>>(hb, fins, finb, nullptr, out);
}